// Round 1
// baseline (132.096 us; speedup 1.0000x reference)
//
#include <hip/hip_runtime.h>
#include <hip/hip_bf16.h>
#include <math.h>

// Problem constants
#define Bv 16
#define Nv 512
#define Ev 256
#define Hv 8
#define Dv 32   // E/H
#define ALPHA 0.2f

// ---------------------------------------------------------------------------
// Kernel A: Wh = x @ W + bW    (M=B*N=8192, K=E=256, N=E=256), fp32
// 64x64 tile per 256-thread block, BK=32, 4x4 micro-tile per thread.
// ---------------------------------------------------------------------------
__global__ __launch_bounds__(256) void wh_gemm(const float* __restrict__ x,
                                               const float* __restrict__ W,
                                               const float* __restrict__ bW,
                                               float* __restrict__ Wh) {
    __shared__ float xs[64][37];  // [m][k], pad 37 -> 2-way max bank conflict on reads
    __shared__ float ws[32][64];  // [k][n]

    const int tid = threadIdx.x;
    const int m0 = blockIdx.x * 64;   // 0..8128
    const int n0 = blockIdx.y * 64;   // 0..192
    const int tx = tid & 15;
    const int ty = tid >> 4;

    float acc[4][4] = {};

    for (int k0 = 0; k0 < Ev; k0 += 32) {
        // load x tile: 64 rows x 32 k = 512 float4
        #pragma unroll
        for (int u = 0; u < 2; ++u) {
            int f = tid + u * 256;       // < 512
            int r = f >> 3, cg = f & 7;  // 8 float4 per row
            float4 v = *(const float4*)&x[(size_t)(m0 + r) * Ev + k0 + cg * 4];
            xs[r][cg * 4 + 0] = v.x;
            xs[r][cg * 4 + 1] = v.y;
            xs[r][cg * 4 + 2] = v.z;
            xs[r][cg * 4 + 3] = v.w;
        }
        // load W tile: 32 k x 64 n = 512 float4
        #pragma unroll
        for (int u = 0; u < 2; ++u) {
            int f = tid + u * 256;
            int kk = f >> 4, ng = f & 15;
            float4 v = *(const float4*)&W[(size_t)(k0 + kk) * Ev + n0 + ng * 4];
            *(float4*)&ws[kk][ng * 4] = v;
        }
        __syncthreads();

        #pragma unroll
        for (int kk = 0; kk < 32; ++kk) {
            float a0 = xs[ty * 4 + 0][kk];
            float a1 = xs[ty * 4 + 1][kk];
            float a2 = xs[ty * 4 + 2][kk];
            float a3 = xs[ty * 4 + 3][kk];
            float4 bv = *(float4*)&ws[kk][tx * 4];
            acc[0][0] += a0 * bv.x; acc[0][1] += a0 * bv.y; acc[0][2] += a0 * bv.z; acc[0][3] += a0 * bv.w;
            acc[1][0] += a1 * bv.x; acc[1][1] += a1 * bv.y; acc[1][2] += a1 * bv.z; acc[1][3] += a1 * bv.w;
            acc[2][0] += a2 * bv.x; acc[2][1] += a2 * bv.y; acc[2][2] += a2 * bv.z; acc[2][3] += a2 * bv.w;
            acc[3][0] += a3 * bv.x; acc[3][1] += a3 * bv.y; acc[3][2] += a3 * bv.z; acc[3][3] += a3 * bv.w;
        }
        __syncthreads();
    }

    float4 bias = *(const float4*)&bW[n0 + tx * 4];
    #pragma unroll
    for (int r = 0; r < 4; ++r) {
        float4 o;
        o.x = acc[r][0] + bias.x;
        o.y = acc[r][1] + bias.y;
        o.z = acc[r][2] + bias.z;
        o.w = acc[r][3] + bias.w;
        *(float4*)&Wh[(size_t)(m0 + ty * 4 + r) * Ev + n0 + tx * 4] = o;
    }
}

// ---------------------------------------------------------------------------
// Kernel B: e12 = Wh @ a + ba -> e1[b,h,i] (col 2h), e2[b,h,j] (col 2h+1)
// 16 rows per 256-thread block; thread (r=tid/16, c=tid%16) computes one dot.
// ---------------------------------------------------------------------------
__global__ __launch_bounds__(256) void e12_kernel(const float* __restrict__ Wh,
                                                  const float* __restrict__ a,
                                                  const float* __restrict__ ba,
                                                  float* __restrict__ e1,
                                                  float* __restrict__ e2) {
    __shared__ float whs[16][260];  // pad 260: 4 distinct banks across the 4 row-groups
    __shared__ float as[256][16];

    const int tid = threadIdx.x;
    const int m0 = blockIdx.x * 16;

    // load 16 Wh rows: 4096 floats = 1024 float4
    #pragma unroll
    for (int u = 0; u < 4; ++u) {
        int f = tid + u * 256;        // < 1024
        int r = f >> 6, c4 = f & 63;  // 64 float4 per row
        float4 v = *(const float4*)&Wh[(size_t)(m0 + r) * Ev + c4 * 4];
        *(float4*)&whs[r][c4 * 4] = v;
    }
    // load a: 256x16 floats = 1024 float4
    #pragma unroll
    for (int u = 0; u < 4; ++u) {
        int f = tid + u * 256;       // < 1024
        int r = f >> 2, c4 = f & 3;  // 4 float4 per row
        float4 v = *(const float4*)&a[(size_t)r * (2 * Hv) + c4 * 4];
        *(float4*)&as[r][c4 * 4] = v;
    }
    __syncthreads();

    const int r = tid >> 4, c = tid & 15;
    float dot = ba[c];
    #pragma unroll 8
    for (int k = 0; k < Ev; ++k) dot += whs[r][k] * as[k][c];

    const int m = m0 + r;
    const int b = m >> 9;       // /512
    const int i = m & 511;
    const int h = c >> 1;
    float* dst = (c & 1) ? e2 : e1;
    dst[(((b << 3) + h) << 9) + i] = dot;
}

// ---------------------------------------------------------------------------
// Kernel C: masked leaky-relu scores -> softmax -> att @ Whh -> relu
// Block = 256 threads (4 waves) handles (b, h, 16 rows).
// LDS: Whh slice [512][32] (64KB) + per-wave p float4[512] (32KB) + e2 (2KB).
// ---------------------------------------------------------------------------
__global__ __launch_bounds__(256) void attn_kernel(const float* __restrict__ A,
                                                   const float* __restrict__ Wh,
                                                   const float* __restrict__ e1g,
                                                   const float* __restrict__ e2g,
                                                   float* __restrict__ out) {
    __shared__ float WhhS[Nv * Dv];   // [j][d]  64KB
    __shared__ float4 pS[4 * Nv];     // per-wave [j] -> (p_r0,p_r1,p_r2,p_r3)  32KB
    __shared__ float e2S[Nv];         // 2KB

    const int tid = threadIdx.x;
    const int i0 = blockIdx.x * 16;
    const int h = blockIdx.y;
    const int b = blockIdx.z;
    const int bh = (b << 3) + h;

    // stage Whh slice: 512 rows x 32 d = 4096 float4
    #pragma unroll
    for (int u = 0; u < 16; ++u) {
        int f = tid + u * 256;       // < 4096
        int j = f >> 3, cg = f & 7;  // 8 float4 per row
        float4 v = *(const float4*)&Wh[((size_t)(b * Nv + j)) * Ev + h * Dv + cg * 4];
        *(float4*)&WhhS[j * Dv + cg * 4] = v;
    }
    e2S[tid] = e2g[(bh << 9) + tid];
    e2S[tid + 256] = e2g[(bh << 9) + tid + 256];
    __syncthreads();

    const int w = tid >> 6;
    const int lane = tid & 63;

    float rinv0 = 0.f, rinv1 = 0.f, rinv2 = 0.f, rinv3 = 0.f;

    // ---- Pass 1: scores + softmax weights (unnormalized) into LDS ----
    #pragma unroll
    for (int r = 0; r < 4; ++r) {
        const int i = i0 + w * 4 + r;
        const float e1v = e1g[(bh << 9) + i];
        const float* Arow = A + ((size_t)b * Nv + i) * Nv;

        float pj[8];
        float m = -INFINITY;
        #pragma unroll
        for (int t = 0; t < 8; ++t) {
            int j = lane + (t << 6);
            float av = Arow[j];
            float ev = e1v + e2S[j];
            ev = (ev > 0.f) ? ev : ALPHA * ev;
            float s = (av > 0.5f) ? ev : -INFINITY;
            pj[t] = s;
            m = fmaxf(m, s);
        }
        #pragma unroll
        for (int off = 32; off; off >>= 1) m = fmaxf(m, __shfl_xor(m, off));

        const bool any = (m != -INFINITY);
        float denom = 0.f;
        #pragma unroll
        for (int t = 0; t < 8; ++t) {
            float p = any ? __expf(pj[t] - m) : 0.f;
            pj[t] = p;
            denom += p;
        }
        #pragma unroll
        for (int off = 32; off; off >>= 1) denom += __shfl_xor(denom, off);
        const float rv = any ? (1.f / denom) : 0.f;
        if (r == 0) rinv0 = rv;
        else if (r == 1) rinv1 = rv;
        else if (r == 2) rinv2 = rv;
        else rinv3 = rv;

        float* pw = (float*)&pS[w * Nv];
        #pragma unroll
        for (int t = 0; t < 8; ++t) {
            int j = lane + (t << 6);
            pw[j * 4 + r] = pj[t];
        }
    }
    __syncthreads();  // uniform; orders pS writes before reads (same-wave anyway)

    // ---- Pass 2: out[4 rows][32 d] = p @ Whh, register-tiled ----
    const int c8 = lane & 7;   // d-group: d = c8*4 .. c8*4+3
    const int jg = lane >> 3;  // j-subgroup 0..7
    float4 a0 = {0, 0, 0, 0}, a1 = a0, a2 = a0, a3 = a0;
    const float4* pw4 = &pS[w * Nv];

    #pragma unroll 8
    for (int t = 0; t < 64; ++t) {
        int jj = (t << 3) + jg;
        float4 wv = *(float4*)&WhhS[jj * Dv + c8 * 4];
        float4 pv = pw4[jj];
        a0.x += pv.x * wv.x; a0.y += pv.x * wv.y; a0.z += pv.x * wv.z; a0.w += pv.x * wv.w;
        a1.x += pv.y * wv.x; a1.y += pv.y * wv.y; a1.z += pv.y * wv.z; a1.w += pv.y * wv.w;
        a2.x += pv.z * wv.x; a2.y += pv.z * wv.y; a2.z += pv.z * wv.z; a2.w += pv.z * wv.w;
        a3.x += pv.w * wv.x; a3.y += pv.w * wv.y; a3.z += pv.w * wv.z; a3.w += pv.w * wv.w;
    }

    // reduce partials across the 8 j-subgroups (lanes differing in bits 3..5)
    #pragma unroll
    for (int off = 8; off < 64; off <<= 1) {
        a0.x += __shfl_xor(a0.x, off); a0.y += __shfl_xor(a0.y, off);
        a0.z += __shfl_xor(a0.z, off); a0.w += __shfl_xor(a0.w, off);
        a1.x += __shfl_xor(a1.x, off); a1.y += __shfl_xor(a1.y, off);
        a1.z += __shfl_xor(a1.z, off); a1.w += __shfl_xor(a1.w, off);
        a2.x += __shfl_xor(a2.x, off); a2.y += __shfl_xor(a2.y, off);
        a2.z += __shfl_xor(a2.z, off); a2.w += __shfl_xor(a2.w, off);
        a3.x += __shfl_xor(a3.x, off); a3.y += __shfl_xor(a3.y, off);
        a3.z += __shfl_xor(a3.z, off); a3.w += __shfl_xor(a3.w, off);
    }

    if (jg < 4) {
        const float rv = (jg == 0) ? rinv0 : (jg == 1) ? rinv1 : (jg == 2) ? rinv2 : rinv3;
        const float4 ar = (jg == 0) ? a0 : (jg == 1) ? a1 : (jg == 2) ? a2 : a3;
        const int i = i0 + w * 4 + jg;
        float4 o;
        o.x = fmaxf(ar.x * rv, 0.f);
        o.y = fmaxf(ar.y * rv, 0.f);
        o.z = fmaxf(ar.z * rv, 0.f);
        o.w = fmaxf(ar.w * rv, 0.f);
        *(float4*)&out[((size_t)(b * Nv + i)) * Ev + h * Dv + c8 * 4] = o;
    }
}

// ---------------------------------------------------------------------------
extern "C" void kernel_launch(void* const* d_in, const int* in_sizes, int n_in,
                              void* d_out, int out_size, void* d_ws, size_t ws_size,
                              hipStream_t stream) {
    const float* x  = (const float*)d_in[0];
    const float* A  = (const float*)d_in[1];
    const float* W  = (const float*)d_in[2];
    const float* bW = (const float*)d_in[3];
    const float* a  = (const float*)d_in[4];
    const float* ba = (const float*)d_in[5];
    float* out = (float*)d_out;

    float* Wh = (float*)d_ws;                       // B*N*E floats = 8 MB
    float* e1 = Wh + (size_t)Bv * Nv * Ev;          // B*H*N floats = 256 KB
    float* e2 = e1 + (size_t)Bv * Hv * Nv;          // B*H*N floats = 256 KB

    wh_gemm<<<dim3(Bv * Nv / 64, Ev / 64), 256, 0, stream>>>(x, W, bW, Wh);
    e12_kernel<<<dim3(Bv * Nv / 16), 256, 0, stream>>>(Wh, a, ba, e1, e2);
    attn_kernel<<<dim3(Nv / 16, Hv, Bv), 256, 0, stream>>>(A, Wh, e1, e2, out);
}

// Round 2
// 97.698 us; speedup vs baseline: 1.3521x; 1.3521x over previous
//
#include <hip/hip_runtime.h>
#include <hip/hip_bf16.h>
#include <math.h>

// Problem constants
#define Bv 16
#define Nv 512
#define Ev 256
#define Hv 8
#define Dv 32   // E/H
#define ALPHA 0.2f

// ---------------------------------------------------------------------------
// Kernel A: Wh = x @ W + bW    (M=B*N=8192, K=E=256, N=E=256), fp32
// 64x64 tile per 256-thread block, BK=32, 4x4 micro-tile per thread.
// ---------------------------------------------------------------------------
__global__ __launch_bounds__(256) void wh_gemm(const float* __restrict__ x,
                                               const float* __restrict__ W,
                                               const float* __restrict__ bW,
                                               float* __restrict__ Wh) {
    __shared__ float xs[64][37];
    __shared__ float ws[32][64];

    const int tid = threadIdx.x;
    const int m0 = blockIdx.x * 64;
    const int n0 = blockIdx.y * 64;
    const int tx = tid & 15;
    const int ty = tid >> 4;

    float acc[4][4] = {};

    for (int k0 = 0; k0 < Ev; k0 += 32) {
        #pragma unroll
        for (int u = 0; u < 2; ++u) {
            int f = tid + u * 256;
            int r = f >> 3, cg = f & 7;
            float4 v = *(const float4*)&x[(size_t)(m0 + r) * Ev + k0 + cg * 4];
            xs[r][cg * 4 + 0] = v.x;
            xs[r][cg * 4 + 1] = v.y;
            xs[r][cg * 4 + 2] = v.z;
            xs[r][cg * 4 + 3] = v.w;
        }
        #pragma unroll
        for (int u = 0; u < 2; ++u) {
            int f = tid + u * 256;
            int kk = f >> 4, ng = f & 15;
            float4 v = *(const float4*)&W[(size_t)(k0 + kk) * Ev + n0 + ng * 4];
            *(float4*)&ws[kk][ng * 4] = v;
        }
        __syncthreads();

        #pragma unroll
        for (int kk = 0; kk < 32; ++kk) {
            float a0 = xs[ty * 4 + 0][kk];
            float a1 = xs[ty * 4 + 1][kk];
            float a2 = xs[ty * 4 + 2][kk];
            float a3 = xs[ty * 4 + 3][kk];
            float4 bv = *(float4*)&ws[kk][tx * 4];
            acc[0][0] += a0 * bv.x; acc[0][1] += a0 * bv.y; acc[0][2] += a0 * bv.z; acc[0][3] += a0 * bv.w;
            acc[1][0] += a1 * bv.x; acc[1][1] += a1 * bv.y; acc[1][2] += a1 * bv.z; acc[1][3] += a1 * bv.w;
            acc[2][0] += a2 * bv.x; acc[2][1] += a2 * bv.y; acc[2][2] += a2 * bv.z; acc[2][3] += a2 * bv.w;
            acc[3][0] += a3 * bv.x; acc[3][1] += a3 * bv.y; acc[3][2] += a3 * bv.z; acc[3][3] += a3 * bv.w;
        }
        __syncthreads();
    }

    float4 bias = *(const float4*)&bW[n0 + tx * 4];
    #pragma unroll
    for (int r = 0; r < 4; ++r) {
        float4 o;
        o.x = acc[r][0] + bias.x;
        o.y = acc[r][1] + bias.y;
        o.z = acc[r][2] + bias.z;
        o.w = acc[r][3] + bias.w;
        *(float4*)&Wh[(size_t)(m0 + ty * 4 + r) * Ev + n0 + tx * 4] = o;
    }
}

// ---------------------------------------------------------------------------
// Kernel B: e12 = Wh @ a + ba -> e1[b,h,i] (col 2h), e2[b,h,j] (col 2h+1)
// ---------------------------------------------------------------------------
__global__ __launch_bounds__(256) void e12_kernel(const float* __restrict__ Wh,
                                                  const float* __restrict__ a,
                                                  const float* __restrict__ ba,
                                                  float* __restrict__ e1,
                                                  float* __restrict__ e2) {
    __shared__ float whs[16][260];
    __shared__ float as[256][16];

    const int tid = threadIdx.x;
    const int m0 = blockIdx.x * 16;

    #pragma unroll
    for (int u = 0; u < 4; ++u) {
        int f = tid + u * 256;
        int r = f >> 6, c4 = f & 63;
        float4 v = *(const float4*)&Wh[(size_t)(m0 + r) * Ev + c4 * 4];
        *(float4*)&whs[r][c4 * 4] = v;
    }
    #pragma unroll
    for (int u = 0; u < 4; ++u) {
        int f = tid + u * 256;
        int r = f >> 2, c4 = f & 3;
        float4 v = *(const float4*)&a[(size_t)r * (2 * Hv) + c4 * 4];
        *(float4*)&as[r][c4 * 4] = v;
    }
    __syncthreads();

    const int r = tid >> 4, c = tid & 15;
    float dot = ba[c];
    #pragma unroll 8
    for (int k = 0; k < Ev; ++k) dot += whs[r][k] * as[k][c];

    const int m = m0 + r;
    const int b = m >> 9;
    const int i = m & 511;
    const int h = c >> 1;
    float* dst = (c & 1) ? e2 : e1;
    dst[(((b << 3) + h) << 9) + i] = dot;
}

// ---------------------------------------------------------------------------
// bf16 round-to-nearest-even pack of two floats into one u32 (lo|hi<<16)
// ---------------------------------------------------------------------------
__device__ __forceinline__ unsigned int pack_bf16(float lo, float hi) {
    unsigned int ul = __builtin_bit_cast(unsigned int, lo);
    unsigned int uh = __builtin_bit_cast(unsigned int, hi);
    ul += 0x7FFFu + ((ul >> 16) & 1u);
    uh += 0x7FFFu + ((uh >> 16) & 1u);
    return (ul >> 16) | (uh & 0xFFFF0000u);
}
__device__ __forceinline__ float bf16_lo(unsigned int u) {
    return __builtin_bit_cast(float, u << 16);
}
__device__ __forceinline__ float bf16_hi(unsigned int u) {
    return __builtin_bit_cast(float, u & 0xFFFF0000u);
}

// ---------------------------------------------------------------------------
// Kernel C: masked leaky-relu scores -> softmax -> att @ Whh -> relu
// Block = 1024 threads (16 waves, 4/SIMD) handles (b, h, 64 rows); wave = 4 rows.
// LDS: Whh [512][32] f32 (64KB) + per-wave p bf16 [128 quads][4 rows][4 j] (64KB)
//      + e2 (2KB) = 130KB -> 1 block/CU but 16 resident waves.
// pS is wave-private: no block barrier between pass1 and pass2.
// ---------------------------------------------------------------------------
__global__ __launch_bounds__(1024) void attn_kernel(const float* __restrict__ A,
                                                    const float* __restrict__ Wh,
                                                    const float* __restrict__ e1g,
                                                    const float* __restrict__ e2g,
                                                    float* __restrict__ out) {
    __shared__ float WhhS[Nv * Dv];          // 64KB [j][d]
    __shared__ unsigned int pS[16 * 1024];   // 64KB: wave-private [q=128][r=4][2 u32]
    __shared__ float e2S[Nv];                // 2KB

    const int tid = threadIdx.x;
    const int i0 = blockIdx.x * 64;
    const int h = blockIdx.y;
    const int b = blockIdx.z;
    const int bh = (b << 3) + h;

    // stage Whh slice: 4096 float4 over 1024 threads
    #pragma unroll
    for (int u = 0; u < 4; ++u) {
        int f = tid + u * 1024;
        int j = f >> 3, cg = f & 7;
        float4 v = *(const float4*)&Wh[((size_t)(b * Nv + j)) * Ev + h * Dv + cg * 4];
        *(float4*)&WhhS[j * Dv + cg * 4] = v;
    }
    if (tid < Nv) e2S[tid] = e2g[(bh << 9) + tid];
    __syncthreads();

    const int w = tid >> 6;
    const int lane = tid & 63;
    unsigned int* pw = pS + w * 1024;

    // this lane's e2 quads (j = 4*lane.. , 256+4*lane..), shared by all 4 rows
    const float4 e2a = *(const float4*)&e2S[lane * 4];
    const float4 e2b = *(const float4*)&e2S[256 + lane * 4];

    // ---- issue all global loads for the wave's 4 rows up front ----
    float4 aA[4], aB[4];
    float e1v[4];
    #pragma unroll
    for (int r = 0; r < 4; ++r) {
        const int i = i0 + w * 4 + r;
        e1v[r] = e1g[(bh << 9) + i];
        const float* Arow = A + ((size_t)b * Nv + i) * Nv;
        aA[r] = *(const float4*)&Arow[lane * 4];
        aB[r] = *(const float4*)&Arow[256 + lane * 4];
    }

    float rv0 = 0.f, rv1 = 0.f, rv2 = 0.f, rv3 = 0.f;

    // ---- Pass 1: masked lrelu scores -> softmax weights (bf16) into pS ----
    #pragma unroll
    for (int r = 0; r < 4; ++r) {
        float p[8];
        {
            float ev;
            ev = e1v[r] + e2a.x; ev = (ev > 0.f) ? ev : ALPHA * ev; p[0] = (aA[r].x > 0.5f) ? ev : -INFINITY;
            ev = e1v[r] + e2a.y; ev = (ev > 0.f) ? ev : ALPHA * ev; p[1] = (aA[r].y > 0.5f) ? ev : -INFINITY;
            ev = e1v[r] + e2a.z; ev = (ev > 0.f) ? ev : ALPHA * ev; p[2] = (aA[r].z > 0.5f) ? ev : -INFINITY;
            ev = e1v[r] + e2a.w; ev = (ev > 0.f) ? ev : ALPHA * ev; p[3] = (aA[r].w > 0.5f) ? ev : -INFINITY;
            ev = e1v[r] + e2b.x; ev = (ev > 0.f) ? ev : ALPHA * ev; p[4] = (aB[r].x > 0.5f) ? ev : -INFINITY;
            ev = e1v[r] + e2b.y; ev = (ev > 0.f) ? ev : ALPHA * ev; p[5] = (aB[r].y > 0.5f) ? ev : -INFINITY;
            ev = e1v[r] + e2b.z; ev = (ev > 0.f) ? ev : ALPHA * ev; p[6] = (aB[r].z > 0.5f) ? ev : -INFINITY;
            ev = e1v[r] + e2b.w; ev = (ev > 0.f) ? ev : ALPHA * ev; p[7] = (aB[r].w > 0.5f) ? ev : -INFINITY;
        }
        float m = fmaxf(fmaxf(fmaxf(p[0], p[1]), fmaxf(p[2], p[3])),
                        fmaxf(fmaxf(p[4], p[5]), fmaxf(p[6], p[7])));
        #pragma unroll
        for (int off = 32; off; off >>= 1) m = fmaxf(m, __shfl_xor(m, off));

        const bool any = (m != -INFINITY);
        float denom = 0.f;
        #pragma unroll
        for (int t = 0; t < 8; ++t) {
            float pe = any ? __expf(p[t] - m) : 0.f;
            p[t] = pe;
            denom += pe;
        }
        #pragma unroll
        for (int off = 32; off; off >>= 1) denom += __shfl_xor(denom, off);
        const float rvr = any ? (1.f / denom) : 0.f;
        if (r == 0) rv0 = rvr; else if (r == 1) rv1 = rvr; else if (r == 2) rv2 = rvr; else rv3 = rvr;

        uint2 qa, qb;
        qa.x = pack_bf16(p[0], p[1]); qa.y = pack_bf16(p[2], p[3]);
        qb.x = pack_bf16(p[4], p[5]); qb.y = pack_bf16(p[6], p[7]);
        *(uint2*)&pw[lane * 8 + r * 2] = qa;         // quad q = lane
        *(uint2*)&pw[(64 + lane) * 8 + r * 2] = qb;  // quad q = 64 + lane
    }

    // wave-private LDS: DS ops are in-order per wave; just stop compiler reordering
    __builtin_amdgcn_wave_barrier();
    asm volatile("" ::: "memory");

    // ---- Pass 2: out[4 rows][32 d] = p @ Whh ----
    const int qg = lane >> 3;  // j-quad group 0..7
    const int c8 = lane & 7;   // d-quad 0..7
    float4 a0 = {0, 0, 0, 0}, a1 = a0, a2 = a0, a3 = a0;

    #pragma unroll 4
    for (int t = 0; t < 16; ++t) {
        const int q = (t << 3) + qg;                 // j = 4q .. 4q+3
        uint4 pq01 = *(uint4*)&pw[q * 8];            // rows 0,1
        uint4 pq23 = *(uint4*)&pw[q * 8 + 4];        // rows 2,3
        float4 wv0 = *(float4*)&WhhS[(q * 4 + 0) * Dv + c8 * 4];
        float4 wv1 = *(float4*)&WhhS[(q * 4 + 1) * Dv + c8 * 4];
        float4 wv2 = *(float4*)&WhhS[(q * 4 + 2) * Dv + c8 * 4];
        float4 wv3 = *(float4*)&WhhS[(q * 4 + 3) * Dv + c8 * 4];

        float p00 = bf16_lo(pq01.x), p01 = bf16_hi(pq01.x), p02 = bf16_lo(pq01.y), p03 = bf16_hi(pq01.y);
        float p10 = bf16_lo(pq01.z), p11 = bf16_hi(pq01.z), p12 = bf16_lo(pq01.w), p13 = bf16_hi(pq01.w);
        float p20 = bf16_lo(pq23.x), p21 = bf16_hi(pq23.x), p22 = bf16_lo(pq23.y), p23 = bf16_hi(pq23.y);
        float p30 = bf16_lo(pq23.z), p31 = bf16_hi(pq23.z), p32 = bf16_lo(pq23.w), p33 = bf16_hi(pq23.w);

        a0.x += p00 * wv0.x + p01 * wv1.x + p02 * wv2.x + p03 * wv3.x;
        a0.y += p00 * wv0.y + p01 * wv1.y + p02 * wv2.y + p03 * wv3.y;
        a0.z += p00 * wv0.z + p01 * wv1.z + p02 * wv2.z + p03 * wv3.z;
        a0.w += p00 * wv0.w + p01 * wv1.w + p02 * wv2.w + p03 * wv3.w;
        a1.x += p10 * wv0.x + p11 * wv1.x + p12 * wv2.x + p13 * wv3.x;
        a1.y += p10 * wv0.y + p11 * wv1.y + p12 * wv2.y + p13 * wv3.y;
        a1.z += p10 * wv0.z + p11 * wv1.z + p12 * wv2.z + p13 * wv3.z;
        a1.w += p10 * wv0.w + p11 * wv1.w + p12 * wv2.w + p13 * wv3.w;
        a2.x += p20 * wv0.x + p21 * wv1.x + p22 * wv2.x + p23 * wv3.x;
        a2.y += p20 * wv0.y + p21 * wv1.y + p22 * wv2.y + p23 * wv3.y;
        a2.z += p20 * wv0.z + p21 * wv1.z + p22 * wv2.z + p23 * wv3.z;
        a2.w += p20 * wv0.w + p21 * wv1.w + p22 * wv2.w + p23 * wv3.w;
        a3.x += p30 * wv0.x + p31 * wv1.x + p32 * wv2.x + p33 * wv3.x;
        a3.y += p30 * wv0.y + p31 * wv1.y + p32 * wv2.y + p33 * wv3.y;
        a3.z += p30 * wv0.z + p31 * wv1.z + p32 * wv2.z + p33 * wv3.z;
        a3.w += p30 * wv0.w + p31 * wv1.w + p32 * wv2.w + p33 * wv3.w;
    }

    // butterfly reduce across the 8 qg groups (lane bits 3..5)
    #pragma unroll
    for (int off = 8; off < 64; off <<= 1) {
        a0.x += __shfl_xor(a0.x, off); a0.y += __shfl_xor(a0.y, off);
        a0.z += __shfl_xor(a0.z, off); a0.w += __shfl_xor(a0.w, off);
        a1.x += __shfl_xor(a1.x, off); a1.y += __shfl_xor(a1.y, off);
        a1.z += __shfl_xor(a1.z, off); a1.w += __shfl_xor(a1.w, off);
        a2.x += __shfl_xor(a2.x, off); a2.y += __shfl_xor(a2.y, off);
        a2.z += __shfl_xor(a2.z, off); a2.w += __shfl_xor(a2.w, off);
        a3.x += __shfl_xor(a3.x, off); a3.y += __shfl_xor(a3.y, off);
        a3.z += __shfl_xor(a3.z, off); a3.w += __shfl_xor(a3.w, off);
    }

    if (qg < 4) {
        const float rvs = (qg == 0) ? rv0 : (qg == 1) ? rv1 : (qg == 2) ? rv2 : rv3;
        const float4 ar = (qg == 0) ? a0 : (qg == 1) ? a1 : (qg == 2) ? a2 : a3;
        const int i = i0 + w * 4 + qg;
        float4 o;
        o.x = fmaxf(ar.x * rvs, 0.f);
        o.y = fmaxf(ar.y * rvs, 0.f);
        o.z = fmaxf(ar.z * rvs, 0.f);
        o.w = fmaxf(ar.w * rvs, 0.f);
        *(float4*)&out[((size_t)(b * Nv + i)) * Ev + h * Dv + c8 * 4] = o;
    }
}

// ---------------------------------------------------------------------------
extern "C" void kernel_launch(void* const* d_in, const int* in_sizes, int n_in,
                              void* d_out, int out_size, void* d_ws, size_t ws_size,
                              hipStream_t stream) {
    const float* x  = (const float*)d_in[0];
    const float* A  = (const float*)d_in[1];
    const float* W  = (const float*)d_in[2];
    const float* bW = (const float*)d_in[3];
    const float* a  = (const float*)d_in[4];
    const float* ba = (const float*)d_in[5];
    float* out = (float*)d_out;

    float* Wh = (float*)d_ws;                       // B*N*E floats = 8 MB
    float* e1 = Wh + (size_t)Bv * Nv * Ev;          // B*H*N floats = 256 KB
    float* e2 = e1 + (size_t)Bv * Hv * Nv;          // B*H*N floats = 256 KB

    wh_gemm<<<dim3(Bv * Nv / 64, Ev / 64), 256, 0, stream>>>(x, W, bW, Wh);
    e12_kernel<<<dim3(Bv * Nv / 16), 256, 0, stream>>>(Wh, a, ba, e1, e2);
    attn_kernel<<<dim3(Nv / 64, Hv, Bv), 1024, 0, stream>>>(A, Wh, e1, e2, out);
}

// Round 3
// 53.902 us; speedup vs baseline: 2.4507x; 1.8125x over previous
//
#include <hip/hip_runtime.h>
#include <math.h>

// Problem constants
#define Bv 16
#define Nv 512
#define Ev 256
#define Hv 8
#define Dv 32   // E/H
#define LOG2E 1.44269504088896340736f

typedef _Float16 half8 __attribute__((ext_vector_type(8)));
typedef _Float16 half4_t __attribute__((ext_vector_type(4)));
typedef float f32x4 __attribute__((ext_vector_type(4)));

// ---------------------------------------------------------------------------
// Kernel A: Wh = x @ W + bW  (M=8192, K=256, N=256) fp32.
// Epilogue also writes WhT[b][h][d][j] in f16 (transposed, per-head) for the
// MFMA attention kernel's B operand.
// ---------------------------------------------------------------------------
__global__ __launch_bounds__(256) void wh_gemm(const float* __restrict__ x,
                                               const float* __restrict__ W,
                                               const float* __restrict__ bW,
                                               float* __restrict__ Wh,
                                               _Float16* __restrict__ WhT) {
    __shared__ float xs[64][37];
    __shared__ float ws[32][64];

    const int tid = threadIdx.x;
    const int m0 = blockIdx.x * 64;
    const int n0 = blockIdx.y * 64;
    const int tx = tid & 15;
    const int ty = tid >> 4;

    float acc[4][4] = {};

    for (int k0 = 0; k0 < Ev; k0 += 32) {
        #pragma unroll
        for (int u = 0; u < 2; ++u) {
            int f = tid + u * 256;
            int r = f >> 3, cg = f & 7;
            float4 v = *(const float4*)&x[(size_t)(m0 + r) * Ev + k0 + cg * 4];
            xs[r][cg * 4 + 0] = v.x;
            xs[r][cg * 4 + 1] = v.y;
            xs[r][cg * 4 + 2] = v.z;
            xs[r][cg * 4 + 3] = v.w;
        }
        #pragma unroll
        for (int u = 0; u < 2; ++u) {
            int f = tid + u * 256;
            int kk = f >> 4, ng = f & 15;
            float4 v = *(const float4*)&W[(size_t)(k0 + kk) * Ev + n0 + ng * 4];
            *(float4*)&ws[kk][ng * 4] = v;
        }
        __syncthreads();

        #pragma unroll
        for (int kk = 0; kk < 32; ++kk) {
            float a0 = xs[ty * 4 + 0][kk];
            float a1 = xs[ty * 4 + 1][kk];
            float a2 = xs[ty * 4 + 2][kk];
            float a3 = xs[ty * 4 + 3][kk];
            float4 bv = *(float4*)&ws[kk][tx * 4];
            acc[0][0] += a0 * bv.x; acc[0][1] += a0 * bv.y; acc[0][2] += a0 * bv.z; acc[0][3] += a0 * bv.w;
            acc[1][0] += a1 * bv.x; acc[1][1] += a1 * bv.y; acc[1][2] += a1 * bv.z; acc[1][3] += a1 * bv.w;
            acc[2][0] += a2 * bv.x; acc[2][1] += a2 * bv.y; acc[2][2] += a2 * bv.z; acc[2][3] += a2 * bv.w;
            acc[3][0] += a3 * bv.x; acc[3][1] += a3 * bv.y; acc[3][2] += a3 * bv.z; acc[3][3] += a3 * bv.w;
        }
        __syncthreads();
    }

    float4 bias = *(const float4*)&bW[n0 + tx * 4];
    #pragma unroll
    for (int r = 0; r < 4; ++r) {
        float4 o;
        o.x = acc[r][0] + bias.x;
        o.y = acc[r][1] + bias.y;
        o.z = acc[r][2] + bias.z;
        o.w = acc[r][3] + bias.w;
        *(float4*)&Wh[(size_t)(m0 + ty * 4 + r) * Ev + n0 + tx * 4] = o;
    }

    // transposed f16 copy: WhT[b][h][d][j], j fastest
    const int mrow = m0 + ty * 4;
    const int gb = mrow >> 9;    // batch
    const int j0 = mrow & 511;   // node index within batch
    #pragma unroll
    for (int c = 0; c < 4; ++c) {
        const int n = n0 + tx * 4 + c;
        const float bc = (c == 0) ? bias.x : (c == 1) ? bias.y : (c == 2) ? bias.z : bias.w;
        half4_t hv;
        hv[0] = (_Float16)(acc[0][c] + bc);
        hv[1] = (_Float16)(acc[1][c] + bc);
        hv[2] = (_Float16)(acc[2][c] + bc);
        hv[3] = (_Float16)(acc[3][c] + bc);
        *(half4_t*)&WhT[(((size_t)gb * Hv + (n >> 5)) * Dv + (n & 31)) * Nv + j0] = hv;
    }
}

// ---------------------------------------------------------------------------
// Kernel B: e12 = Wh @ a + ba -> e1[b,h,i] (col 2h), e2[b,h,j] (col 2h+1)
// ---------------------------------------------------------------------------
__global__ __launch_bounds__(256) void e12_kernel(const float* __restrict__ Wh,
                                                  const float* __restrict__ a,
                                                  const float* __restrict__ ba,
                                                  float* __restrict__ e1,
                                                  float* __restrict__ e2) {
    __shared__ float whs[16][260];
    __shared__ float as[256][16];

    const int tid = threadIdx.x;
    const int m0 = blockIdx.x * 16;

    #pragma unroll
    for (int u = 0; u < 4; ++u) {
        int f = tid + u * 256;
        int r = f >> 6, c4 = f & 63;
        float4 v = *(const float4*)&Wh[(size_t)(m0 + r) * Ev + c4 * 4];
        *(float4*)&whs[r][c4 * 4] = v;
    }
    #pragma unroll
    for (int u = 0; u < 4; ++u) {
        int f = tid + u * 256;
        int r = f >> 2, c4 = f & 3;
        float4 v = *(const float4*)&a[(size_t)r * (2 * Hv) + c4 * 4];
        *(float4*)&as[r][c4 * 4] = v;
    }
    __syncthreads();

    const int r = tid >> 4, c = tid & 15;
    float dot = ba[c];
    #pragma unroll 8
    for (int k = 0; k < Ev; ++k) dot += whs[r][k] * as[k][c];

    const int m = m0 + r;
    const int b = m >> 9;
    const int i = m & 511;
    const int h = c >> 1;
    float* dst = (c & 1) ? e2 : e1;
    dst[(((b << 3) + h) << 9) + i] = dot;
}

// ---------------------------------------------------------------------------
// Kernel C: fused masked-lrelu-softmax + PV via MFMA 16x16x32 f16.
// Block = 256 threads (4 waves) x (b, h, 64 rows); each wave owns 16 rows.
// No max-subtraction (scores bounded: |e1+e2| small); denominator applied in
// epilogue; empty rows -> denom 0 -> out 0.
// Lane (row=l&15, strip=l>>4) computes p for j = t*32 + strip*8 + e — exactly
// the MFMA A-fragment layout, so p never leaves registers.
// ---------------------------------------------------------------------------
__global__ __launch_bounds__(256) void attn_kernel(const float* __restrict__ A,
                                                   const _Float16* __restrict__ WhT,
                                                   const float* __restrict__ e1g,
                                                   const float* __restrict__ e2g,
                                                   float* __restrict__ out) {
    __shared__ _Float16 whT[Dv * Nv];  // 32KB, rows of 512 f16; 16B-blocks XOR-swizzled by (d&7)
    __shared__ float e2S[Nv];          // pre-scaled by log2(e)

    const int tid = threadIdx.x;
    const int i0 = blockIdx.x * 64;
    const int h = blockIdx.y;
    const int b = blockIdx.z;
    const int bh = (b << 3) + h;

    // stage WhT slice (coalesced 16B/lane reads; swizzled conflict-free writes)
    const _Float16* src = WhT + (size_t)bh * (Dv * Nv);
    #pragma unroll
    for (int u = 0; u < 8; ++u) {
        int f = tid + u * 256;
        int d = f >> 6, blk = f & 63;
        uint4 v = *(const uint4*)(src + d * Nv + blk * 8);
        *(uint4*)&whT[d * Nv + ((blk ^ (d & 7)) * 8)] = v;
    }
    e2S[tid] = e2g[(bh << 9) + tid] * LOG2E;
    e2S[tid + 256] = e2g[(bh << 9) + tid + 256] * LOG2E;
    __syncthreads();

    const int w = tid >> 6;
    const int lane = tid & 63;
    const int row = lane & 15;
    const int strip = lane >> 4;
    const int i = i0 + (w << 4) + row;

    const float e1v = e1g[(bh << 9) + i] * LOG2E;
    const float* Arow = A + ((size_t)b * Nv + i) * Nv + (strip << 3);

    const int d0 = lane & 15;
    const int sw = d0 & 7;
    const _Float16* brow0 = &whT[d0 * Nv];
    const _Float16* brow1 = &whT[(16 + d0) * Nv];

    f32x4 acc0 = {0.f, 0.f, 0.f, 0.f};
    f32x4 acc1 = {0.f, 0.f, 0.f, 0.f};
    float denom = 0.f;

    #pragma unroll 4
    for (int t = 0; t < 16; ++t) {
        const float4 av0 = *(const float4*)(Arow + t * 32);
        const float4 av1 = *(const float4*)(Arow + t * 32 + 4);
        const float4 e2a = *(const float4*)&e2S[t * 32 + (strip << 3)];
        const float4 e2b = *(const float4*)&e2S[t * 32 + (strip << 3) + 4];

        float s0 = e1v + e2a.x, s1 = e1v + e2a.y, s2 = e1v + e2a.z, s3 = e1v + e2a.w;
        float s4 = e1v + e2b.x, s5 = e1v + e2b.y, s6 = e1v + e2b.z, s7 = e1v + e2b.w;
        s0 = fmaxf(s0, 0.2f * s0); s1 = fmaxf(s1, 0.2f * s1);
        s2 = fmaxf(s2, 0.2f * s2); s3 = fmaxf(s3, 0.2f * s3);
        s4 = fmaxf(s4, 0.2f * s4); s5 = fmaxf(s5, 0.2f * s5);
        s6 = fmaxf(s6, 0.2f * s6); s7 = fmaxf(s7, 0.2f * s7);
        // p = A * 2^s  (A is exactly 0.0 or 1.0)
        float q0 = __builtin_amdgcn_exp2f(s0) * av0.x;
        float q1 = __builtin_amdgcn_exp2f(s1) * av0.y;
        float q2 = __builtin_amdgcn_exp2f(s2) * av0.z;
        float q3 = __builtin_amdgcn_exp2f(s3) * av0.w;
        float q4 = __builtin_amdgcn_exp2f(s4) * av1.x;
        float q5 = __builtin_amdgcn_exp2f(s5) * av1.y;
        float q6 = __builtin_amdgcn_exp2f(s6) * av1.z;
        float q7 = __builtin_amdgcn_exp2f(s7) * av1.w;
        denom += ((q0 + q1) + (q2 + q3)) + ((q4 + q5) + (q6 + q7));

        half8 af;
        af[0] = (_Float16)q0; af[1] = (_Float16)q1;
        af[2] = (_Float16)q2; af[3] = (_Float16)q3;
        af[4] = (_Float16)q4; af[5] = (_Float16)q5;
        af[6] = (_Float16)q6; af[7] = (_Float16)q7;

        const int blk = ((t << 2) + strip) ^ sw;
        half8 b0 = *(const half8*)(brow0 + blk * 8);
        half8 b1 = *(const half8*)(brow1 + blk * 8);
        acc0 = __builtin_amdgcn_mfma_f32_16x16x32_f16(af, b0, acc0, 0, 0, 0);
        acc1 = __builtin_amdgcn_mfma_f32_16x16x32_f16(af, b1, acc1, 0, 0, 0);
    }

    // full row denominators: strips of a row are lanes {l, l^16, l^32, l^48}
    denom += __shfl_xor(denom, 16);
    denom += __shfl_xor(denom, 32);

    // C/D layout: col = lane&15, row = strip*4 + e
    #pragma unroll
    for (int e = 0; e < 4; ++e) {
        const float dn = __shfl(denom, (strip << 2) + e);  // lane r holds row r's denom
        const float rv = (dn > 0.f) ? (1.f / dn) : 0.f;
        const int orow = i0 + (w << 4) + (strip << 2) + e;
        float* orp = &out[((size_t)b * Nv + orow) * Ev + (h << 5)];
        orp[d0] = fmaxf(acc0[e] * rv, 0.f);
        orp[16 + d0] = fmaxf(acc1[e] * rv, 0.f);
    }
}

// ---------------------------------------------------------------------------
// Scratch plan: Wh(f32, 8MB) lives in d_out (dead after e12; attn only reads
// WhT/e1/e2/A and then overwrites d_out). d_ws: WhT f16 4MB + e1/e2 512KB.
// ---------------------------------------------------------------------------
extern "C" void kernel_launch(void* const* d_in, const int* in_sizes, int n_in,
                              void* d_out, int out_size, void* d_ws, size_t ws_size,
                              hipStream_t stream) {
    const float* x  = (const float*)d_in[0];
    const float* A  = (const float*)d_in[1];
    const float* W  = (const float*)d_in[2];
    const float* bW = (const float*)d_in[3];
    const float* a  = (const float*)d_in[4];
    const float* ba = (const float*)d_in[5];
    float* out = (float*)d_out;

    float* Wh = (float*)d_out;                          // B*N*E f32 = out_size exactly
    _Float16* WhT = (_Float16*)d_ws;                    // B*H*D*N f16 = 4MB
    float* e1 = (float*)((char*)d_ws + (size_t)Bv * Hv * Dv * Nv * 2);
    float* e2 = e1 + (size_t)Bv * Hv * Nv;

    wh_gemm<<<dim3(Bv * Nv / 64, Ev / 64), 256, 0, stream>>>(x, W, bW, Wh, WhT);
    e12_kernel<<<dim3(Bv * Nv / 16), 256, 0, stream>>>(Wh, a, ba, e1, e2);
    attn_kernel<<<dim3(Nv / 64, Hv, Bv), 256, 0, stream>>>(A, WhT, e1, e2, out);
}

// Round 4
// 51.923 us; speedup vs baseline: 2.5441x; 1.0381x over previous
//
#include <hip/hip_runtime.h>
#include <math.h>

// Problem constants
#define Bv 16
#define Nv 512
#define Ev 256
#define Hv 8
#define Dv 32   // E/H
#define LOG2E 1.44269504088896340736f

typedef _Float16 half8 __attribute__((ext_vector_type(8)));
typedef _Float16 half4_t __attribute__((ext_vector_type(4)));
typedef float f32x4 __attribute__((ext_vector_type(4)));

// ---------------------------------------------------------------------------
// Kernel 0: prep.
//  blocks 0..63 : WT[f][e] = f16(W[e][f])   (32x32 tiles via LDS)
//  blocks 64..79: Wa[e][c] = sum_f W[e][f] * a[f][c]   (f32, 16 rows/block)
//  block  80    : cba[c]   = sum_f bW[f] * a[f][c] + ba[c]
// ---------------------------------------------------------------------------
__global__ __launch_bounds__(256) void prep_kernel(const float* __restrict__ W,
                                                   const float* __restrict__ aP,
                                                   const float* __restrict__ bW,
                                                   const float* __restrict__ ba,
                                                   _Float16* __restrict__ WT,
                                                   float* __restrict__ Wa,
                                                   float* __restrict__ cba) {
    __shared__ float t[32][33];
    const int tid = threadIdx.x;
    const int blk = blockIdx.x;

    if (blk < 64) {
        const int k0 = (blk >> 3) * 32, n0 = (blk & 7) * 32;
        *(float4*)&t[tid >> 3][(tid & 7) * 4] =
            *(const float4*)&W[(size_t)(k0 + (tid >> 3)) * Ev + n0 + (tid & 7) * 4];
        __syncthreads();
        const int nn = tid >> 3, kg = (tid & 7) * 4;
        half4_t hv;
        hv[0] = (_Float16)t[kg + 0][nn];
        hv[1] = (_Float16)t[kg + 1][nn];
        hv[2] = (_Float16)t[kg + 2][nn];
        hv[3] = (_Float16)t[kg + 3][nn];
        *(half4_t*)&WT[(size_t)(n0 + nn) * Ev + k0 + kg] = hv;
    } else if (blk < 80) {
        const int e = (blk - 64) * 16 + (tid >> 4);
        const int c = tid & 15;
        float dot = 0.f;
        for (int k4 = 0; k4 < 64; ++k4) {
            float4 wv = *(const float4*)&W[(size_t)e * Ev + k4 * 4];
            dot += wv.x * aP[(k4 * 4 + 0) * 16 + c];
            dot += wv.y * aP[(k4 * 4 + 1) * 16 + c];
            dot += wv.z * aP[(k4 * 4 + 2) * 16 + c];
            dot += wv.w * aP[(k4 * 4 + 3) * 16 + c];
        }
        Wa[e * 16 + c] = dot;
    } else {
        if (tid < 16) {
            float d = ba[tid];
            for (int k = 0; k < Ev; ++k) d += bW[k] * aP[k * 16 + tid];
            cba[tid] = d;
        }
    }
}

// ---------------------------------------------------------------------------
// Kernel 1: WhT[b][h][d][j] = f16( (x @ W + bW) transposed per head )
// MFMA f16 16x16x32. 64(m) x 64(n) tile, BK=32, 4 waves (wave w = m-rows
// w*16..w*16+15, all 64 n). A-frag: row=lane&15, k=(lane>>4)*8+e.
// B-frag: col=lane&15, k=(lane>>4)*8+e (layouts verified by round-3 attn).
// Epilogue transposes through LDS for coalesced 32B global stores.
// ---------------------------------------------------------------------------
__global__ __launch_bounds__(256) void whT_gemm(const float* __restrict__ x,
                                                const _Float16* __restrict__ WT,
                                                const float* __restrict__ bW,
                                                _Float16* __restrict__ WhT) {
    __shared__ _Float16 xs[64][40];    // [m][k] pad 40
    __shared__ _Float16 wsT[64][40];   // [n][k] pad 40
    __shared__ _Float16 ldsTr[64][72]; // [n][j] epilogue transpose

    const int tid = threadIdx.x;
    const int m0 = blockIdx.x * 64;
    const int n0 = blockIdx.y * 64;
    const int w = tid >> 6;
    const int lane = tid & 63;
    const int row = lane & 15;
    const int strip = lane >> 4;

    f32x4 acc[4] = {{0.f, 0.f, 0.f, 0.f}, {0.f, 0.f, 0.f, 0.f},
                    {0.f, 0.f, 0.f, 0.f}, {0.f, 0.f, 0.f, 0.f}};

    const int sr = tid >> 2;            // staging row 0..63
    const int skg = (tid & 3) * 8;      // staging k-offset 0,8,16,24

    for (int k0 = 0; k0 < Ev; k0 += 32) {
        // stage x tile (f32 -> f16)
        {
            const float* xp = &x[(size_t)(m0 + sr) * Ev + k0 + skg];
            float4 v0 = *(const float4*)xp;
            float4 v1 = *(const float4*)(xp + 4);
            half8 hv;
            hv[0] = (_Float16)v0.x; hv[1] = (_Float16)v0.y;
            hv[2] = (_Float16)v0.z; hv[3] = (_Float16)v0.w;
            hv[4] = (_Float16)v1.x; hv[5] = (_Float16)v1.y;
            hv[6] = (_Float16)v1.z; hv[7] = (_Float16)v1.w;
            *(half8*)&xs[sr][skg] = hv;
        }
        // stage WT tile (already f16, already [n][k])
        {
            half8 hv = *(const half8*)&WT[(size_t)(n0 + sr) * Ev + k0 + skg];
            *(half8*)&wsT[sr][skg] = hv;
        }
        __syncthreads();

        half8 af = *(const half8*)&xs[w * 16 + row][strip * 8];
        #pragma unroll
        for (int ns = 0; ns < 4; ++ns) {
            half8 bf = *(const half8*)&wsT[ns * 16 + row][strip * 8];
            acc[ns] = __builtin_amdgcn_mfma_f32_16x16x32_f16(af, bf, acc[ns], 0, 0, 0);
        }
        __syncthreads();
    }

    // epilogue: add bias, cvt f16, transpose via LDS
    #pragma unroll
    for (int ns = 0; ns < 4; ++ns) {
        const float bias = bW[n0 + ns * 16 + row];  // col = lane&15
        half4_t hv;
        hv[0] = (_Float16)(acc[ns][0] + bias);
        hv[1] = (_Float16)(acc[ns][1] + bias);
        hv[2] = (_Float16)(acc[ns][2] + bias);
        hv[3] = (_Float16)(acc[ns][3] + bias);
        // C/D: col=lane&15 (n), rows j_local = w*16 + strip*4 + e
        *(half4_t*)&ldsTr[ns * 16 + row][w * 16 + strip * 4] = hv;
    }
    __syncthreads();

    // readout: thread -> (n = tid>>2, jg = tid&3), 32B contiguous j
    {
        const int n = tid >> 2, jg = tid & 3;
        uint4 v0 = *(const uint4*)&ldsTr[n][jg * 16];
        uint4 v1 = *(const uint4*)&ldsTr[n][jg * 16 + 8];
        const int ng = n0 + n;
        const int h = ng >> 5, d = ng & 31;
        const int b = m0 >> 9, j0 = m0 & 511;
        _Float16* dst = &WhT[(((size_t)b * Hv + h) * Dv + d) * Nv + j0 + jg * 16];
        *(uint4*)dst = v0;
        *(uint4*)(dst + 8) = v1;
    }
}

// ---------------------------------------------------------------------------
// Kernel 2: e12 = x @ Wa + cba -> e1[b,h,i] (even cols), e2[b,h,j] (odd cols)
// 32 rows/block; 8 threads per row = 4 col-quads x 2 k-halves; f32 exact.
// ---------------------------------------------------------------------------
__global__ __launch_bounds__(256) void e12_kernel(const float* __restrict__ x,
                                                  const float* __restrict__ Wa,
                                                  const float* __restrict__ cba,
                                                  float* __restrict__ e1,
                                                  float* __restrict__ e2) {
    __shared__ float WaS[Ev][16];
    __shared__ float cbaS[16];

    const int tid = threadIdx.x;
    const int m0 = blockIdx.x * 32;

    #pragma unroll
    for (int u = 0; u < 4; ++u) {
        int f = tid + u * 256;
        *(float4*)&WaS[f >> 2][(f & 3) * 4] = *(const float4*)&Wa[f * 4];
    }
    if (tid < 16) cbaS[tid] = cba[tid];
    __syncthreads();

    const int r = tid >> 3;
    const int q = (tid >> 1) & 3;  // col quad: c = q*4..q*4+3
    const int kh = tid & 1;        // k half
    const int m = m0 + r;

    const float* xr = &x[(size_t)m * Ev + kh * 128];
    float4 acc = {0.f, 0.f, 0.f, 0.f};

    #pragma unroll 8
    for (int it = 0; it < 32; ++it) {
        float4 xv = *(const float4*)&xr[it * 4];
        const int kb = kh * 128 + it * 4;
        float4 w0 = *(const float4*)&WaS[kb + 0][q * 4];
        float4 w1 = *(const float4*)&WaS[kb + 1][q * 4];
        float4 w2 = *(const float4*)&WaS[kb + 2][q * 4];
        float4 w3 = *(const float4*)&WaS[kb + 3][q * 4];
        acc.x += xv.x * w0.x + xv.y * w1.x + xv.z * w2.x + xv.w * w3.x;
        acc.y += xv.x * w0.y + xv.y * w1.y + xv.z * w2.y + xv.w * w3.y;
        acc.z += xv.x * w0.z + xv.y * w1.z + xv.z * w2.z + xv.w * w3.z;
        acc.w += xv.x * w0.w + xv.y * w1.w + xv.z * w2.w + xv.w * w3.w;
    }

    acc.x += __shfl_xor(acc.x, 1);
    acc.y += __shfl_xor(acc.y, 1);
    acc.z += __shfl_xor(acc.z, 1);
    acc.w += __shfl_xor(acc.w, 1);

    if (kh == 0) {
        const int b = m >> 9, i = m & 511;
        #pragma unroll
        for (int cc = 0; cc < 4; ++cc) {
            const int c = q * 4 + cc;
            const float val = ((cc == 0) ? acc.x : (cc == 1) ? acc.y : (cc == 2) ? acc.z : acc.w)
                              + cbaS[c];
            const int h = c >> 1;
            float* dst = (c & 1) ? e2 : e1;
            dst[(((b << 3) + h) << 9) + i] = val;
        }
    }
}

// ---------------------------------------------------------------------------
// Kernel 3: fused masked-lrelu-softmax + PV via MFMA 16x16x32 f16.
// (unchanged from round 3 — passed at absmax 9.8e-4)
// ---------------------------------------------------------------------------
__global__ __launch_bounds__(256) void attn_kernel(const float* __restrict__ A,
                                                   const _Float16* __restrict__ WhT,
                                                   const float* __restrict__ e1g,
                                                   const float* __restrict__ e2g,
                                                   float* __restrict__ out) {
    __shared__ _Float16 whT[Dv * Nv];  // 32KB, 16B-blocks XOR-swizzled by (d&7)
    __shared__ float e2S[Nv];

    const int tid = threadIdx.x;
    const int i0 = blockIdx.x * 64;
    const int h = blockIdx.y;
    const int b = blockIdx.z;
    const int bh = (b << 3) + h;

    const _Float16* src = WhT + (size_t)bh * (Dv * Nv);
    #pragma unroll
    for (int u = 0; u < 8; ++u) {
        int f = tid + u * 256;
        int d = f >> 6, blk = f & 63;
        uint4 v = *(const uint4*)(src + d * Nv + blk * 8);
        *(uint4*)&whT[d * Nv + ((blk ^ (d & 7)) * 8)] = v;
    }
    e2S[tid] = e2g[(bh << 9) + tid] * LOG2E;
    e2S[tid + 256] = e2g[(bh << 9) + tid + 256] * LOG2E;
    __syncthreads();

    const int w = tid >> 6;
    const int lane = tid & 63;
    const int row = lane & 15;
    const int strip = lane >> 4;
    const int i = i0 + (w << 4) + row;

    const float e1v = e1g[(bh << 9) + i] * LOG2E;
    const float* Arow = A + ((size_t)b * Nv + i) * Nv + (strip << 3);

    const int d0 = lane & 15;
    const int sw = d0 & 7;
    const _Float16* brow0 = &whT[d0 * Nv];
    const _Float16* brow1 = &whT[(16 + d0) * Nv];

    f32x4 acc0 = {0.f, 0.f, 0.f, 0.f};
    f32x4 acc1 = {0.f, 0.f, 0.f, 0.f};
    float denom = 0.f;

    #pragma unroll 4
    for (int t = 0; t < 16; ++t) {
        const float4 av0 = *(const float4*)(Arow + t * 32);
        const float4 av1 = *(const float4*)(Arow + t * 32 + 4);
        const float4 e2a = *(const float4*)&e2S[t * 32 + (strip << 3)];
        const float4 e2b = *(const float4*)&e2S[t * 32 + (strip << 3) + 4];

        float s0 = e1v + e2a.x, s1 = e1v + e2a.y, s2 = e1v + e2a.z, s3 = e1v + e2a.w;
        float s4 = e1v + e2b.x, s5 = e1v + e2b.y, s6 = e1v + e2b.z, s7 = e1v + e2b.w;
        s0 = fmaxf(s0, 0.2f * s0); s1 = fmaxf(s1, 0.2f * s1);
        s2 = fmaxf(s2, 0.2f * s2); s3 = fmaxf(s3, 0.2f * s3);
        s4 = fmaxf(s4, 0.2f * s4); s5 = fmaxf(s5, 0.2f * s5);
        s6 = fmaxf(s6, 0.2f * s6); s7 = fmaxf(s7, 0.2f * s7);
        float q0 = __builtin_amdgcn_exp2f(s0) * av0.x;
        float q1 = __builtin_amdgcn_exp2f(s1) * av0.y;
        float q2 = __builtin_amdgcn_exp2f(s2) * av0.z;
        float q3 = __builtin_amdgcn_exp2f(s3) * av0.w;
        float q4 = __builtin_amdgcn_exp2f(s4) * av1.x;
        float q5 = __builtin_amdgcn_exp2f(s5) * av1.y;
        float q6 = __builtin_amdgcn_exp2f(s6) * av1.z;
        float q7 = __builtin_amdgcn_exp2f(s7) * av1.w;
        denom += ((q0 + q1) + (q2 + q3)) + ((q4 + q5) + (q6 + q7));

        half8 af;
        af[0] = (_Float16)q0; af[1] = (_Float16)q1;
        af[2] = (_Float16)q2; af[3] = (_Float16)q3;
        af[4] = (_Float16)q4; af[5] = (_Float16)q5;
        af[6] = (_Float16)q6; af[7] = (_Float16)q7;

        const int blk = ((t << 2) + strip) ^ sw;
        half8 b0 = *(const half8*)(brow0 + blk * 8);
        half8 b1 = *(const half8*)(brow1 + blk * 8);
        acc0 = __builtin_amdgcn_mfma_f32_16x16x32_f16(af, b0, acc0, 0, 0, 0);
        acc1 = __builtin_amdgcn_mfma_f32_16x16x32_f16(af, b1, acc1, 0, 0, 0);
    }

    denom += __shfl_xor(denom, 16);
    denom += __shfl_xor(denom, 32);

    #pragma unroll
    for (int e = 0; e < 4; ++e) {
        const float dn = __shfl(denom, (strip << 2) + e);
        const float rv = (dn > 0.f) ? (1.f / dn) : 0.f;
        const int orow = i0 + (w << 4) + (strip << 2) + e;
        float* orp = &out[((size_t)b * Nv + orow) * Ev + (h << 5)];
        orp[d0] = fmaxf(acc0[e] * rv, 0.f);
        orp[16 + d0] = fmaxf(acc1[e] * rv, 0.f);
    }
}

// ---------------------------------------------------------------------------
// Workspace: WT f16 128KB | Wa f32 16KB | cba 256B | WhT f16 4MB | e1,e2 512KB
// ---------------------------------------------------------------------------
extern "C" void kernel_launch(void* const* d_in, const int* in_sizes, int n_in,
                              void* d_out, int out_size, void* d_ws, size_t ws_size,
                              hipStream_t stream) {
    const float* x  = (const float*)d_in[0];
    const float* A  = (const float*)d_in[1];
    const float* W  = (const float*)d_in[2];
    const float* bW = (const float*)d_in[3];
    const float* a  = (const float*)d_in[4];
    const float* ba = (const float*)d_in[5];
    float* out = (float*)d_out;

    char* ws = (char*)d_ws;
    _Float16* WT  = (_Float16*)ws;                              // 128KB
    float*    Wa  = (float*)(ws + 131072);                      // 16KB
    float*    cba = (float*)(ws + 131072 + 16384);              // 256B
    _Float16* WhT = (_Float16*)(ws + 131072 + 16384 + 256);     // 4MB
    float*    e1  = (float*)(ws + 131072 + 16384 + 256 + 4194304);
    float*    e2  = e1 + (size_t)Bv * Hv * Nv;

    prep_kernel<<<81, 256, 0, stream>>>(W, a, bW, ba, WT, Wa, cba);
    whT_gemm<<<dim3(Bv * Nv / 64, Ev / 64), 256, 0, stream>>>(x, WT, bW, WhT);
    e12_kernel<<<dim3(Bv * Nv / 32), 256, 0, stream>>>(x, Wa, cba, e1, e2);
    attn_kernel<<<dim3(Nv / 64, Hv, Bv), 256, 0, stream>>>(A, WhT, e1, e2, out);
}

// Round 5
// 45.270 us; speedup vs baseline: 2.9179x; 1.1470x over previous
//
#include <hip/hip_runtime.h>
#include <math.h>

// Problem constants
#define Bv 16
#define Nv 512
#define Ev 256
#define Hv 8
#define Dv 32   // E/H
#define LOG2E 1.44269504088896340736f

typedef _Float16 half8 __attribute__((ext_vector_type(8)));
typedef _Float16 half4_t __attribute__((ext_vector_type(4)));
typedef float f32x4 __attribute__((ext_vector_type(4)));

// ---------------------------------------------------------------------------
// Kernel 0: prep.
//  blocks 0..63   : WT[f][e] = f16(W[e][f])   (32x32 tiles via LDS)
//  blocks 64..79  : Wa[e][c] = sum_f W[e][f] * a[f][c]   (f32)
//  block  80      : cba[c]   = sum_f bW[f] * a[f][c] + ba[c]
//  blocks 81..2128: Abm bit-pack of A via wave ballot (bit j of dword = A>0.5)
// ---------------------------------------------------------------------------
__global__ __launch_bounds__(256) void prep_kernel(const float* __restrict__ W,
                                                   const float* __restrict__ aP,
                                                   const float* __restrict__ bW,
                                                   const float* __restrict__ ba,
                                                   const float* __restrict__ A,
                                                   _Float16* __restrict__ WT,
                                                   float* __restrict__ Wa,
                                                   float* __restrict__ cba,
                                                   unsigned int* __restrict__ Abm) {
    __shared__ float t[32][33];
    const int tid = threadIdx.x;
    const int blk = blockIdx.x;

    if (blk < 64) {
        const int k0 = (blk >> 3) * 32, n0 = (blk & 7) * 32;
        *(float4*)&t[tid >> 3][(tid & 7) * 4] =
            *(const float4*)&W[(size_t)(k0 + (tid >> 3)) * Ev + n0 + (tid & 7) * 4];
        __syncthreads();
        const int nn = tid >> 3, kg = (tid & 7) * 4;
        half4_t hv;
        hv[0] = (_Float16)t[kg + 0][nn];
        hv[1] = (_Float16)t[kg + 1][nn];
        hv[2] = (_Float16)t[kg + 2][nn];
        hv[3] = (_Float16)t[kg + 3][nn];
        *(half4_t*)&WT[(size_t)(n0 + nn) * Ev + k0 + kg] = hv;
    } else if (blk < 80) {
        const int e = (blk - 64) * 16 + (tid >> 4);
        const int c = tid & 15;
        float dot = 0.f;
        for (int k4 = 0; k4 < 64; ++k4) {
            float4 wv = *(const float4*)&W[(size_t)e * Ev + k4 * 4];
            dot += wv.x * aP[(k4 * 4 + 0) * 16 + c];
            dot += wv.y * aP[(k4 * 4 + 1) * 16 + c];
            dot += wv.z * aP[(k4 * 4 + 2) * 16 + c];
            dot += wv.w * aP[(k4 * 4 + 3) * 16 + c];
        }
        Wa[e * 16 + c] = dot;
    } else if (blk == 80) {
        if (tid < 16) {
            float d = ba[tid];
            for (int k = 0; k < Ev; ++k) d += bW[k] * aP[k * 16 + tid];
            cba[tid] = d;
        }
    } else {
        // A bit-pack: block covers 2048 consecutive floats (4 rows of 512).
        // wave w handles one row; 8 ballot rounds of 64 consecutive floats.
        const int ablk = blk - 81;
        const int w = tid >> 6, lane = tid & 63;
        const size_t base = (size_t)ablk * 2048 + w * 512;
        #pragma unroll
        for (int r = 0; r < 8; ++r) {
            const size_t f = base + r * 64 + lane;
            const bool pred = A[f] > 0.5f;
            unsigned long long m = __ballot(pred);
            if (lane == 0) *(unsigned long long*)&Abm[f >> 5] = m;
        }
    }
}

// ---------------------------------------------------------------------------
// Kernel 1: WhT[b][h][d][j] = f16( (x @ W + bW) transposed per head )
// MFMA f16 16x16x32, 64x64 tile, BK=32. (unchanged from round 4)
// ---------------------------------------------------------------------------
__global__ __launch_bounds__(256) void whT_gemm(const float* __restrict__ x,
                                                const _Float16* __restrict__ WT,
                                                const float* __restrict__ bW,
                                                _Float16* __restrict__ WhT) {
    __shared__ _Float16 xs[64][40];
    __shared__ _Float16 wsT[64][40];
    __shared__ _Float16 ldsTr[64][72];

    const int tid = threadIdx.x;
    const int m0 = blockIdx.x * 64;
    const int n0 = blockIdx.y * 64;
    const int w = tid >> 6;
    const int lane = tid & 63;
    const int row = lane & 15;
    const int strip = lane >> 4;

    f32x4 acc[4] = {{0.f, 0.f, 0.f, 0.f}, {0.f, 0.f, 0.f, 0.f},
                    {0.f, 0.f, 0.f, 0.f}, {0.f, 0.f, 0.f, 0.f}};

    const int sr = tid >> 2;
    const int skg = (tid & 3) * 8;

    for (int k0 = 0; k0 < Ev; k0 += 32) {
        {
            const float* xp = &x[(size_t)(m0 + sr) * Ev + k0 + skg];
            float4 v0 = *(const float4*)xp;
            float4 v1 = *(const float4*)(xp + 4);
            half8 hv;
            hv[0] = (_Float16)v0.x; hv[1] = (_Float16)v0.y;
            hv[2] = (_Float16)v0.z; hv[3] = (_Float16)v0.w;
            hv[4] = (_Float16)v1.x; hv[5] = (_Float16)v1.y;
            hv[6] = (_Float16)v1.z; hv[7] = (_Float16)v1.w;
            *(half8*)&xs[sr][skg] = hv;
        }
        {
            half8 hv = *(const half8*)&WT[(size_t)(n0 + sr) * Ev + k0 + skg];
            *(half8*)&wsT[sr][skg] = hv;
        }
        __syncthreads();

        half8 af = *(const half8*)&xs[w * 16 + row][strip * 8];
        #pragma unroll
        for (int ns = 0; ns < 4; ++ns) {
            half8 bf = *(const half8*)&wsT[ns * 16 + row][strip * 8];
            acc[ns] = __builtin_amdgcn_mfma_f32_16x16x32_f16(af, bf, acc[ns], 0, 0, 0);
        }
        __syncthreads();
    }

    #pragma unroll
    for (int ns = 0; ns < 4; ++ns) {
        const float bias = bW[n0 + ns * 16 + row];
        half4_t hv;
        hv[0] = (_Float16)(acc[ns][0] + bias);
        hv[1] = (_Float16)(acc[ns][1] + bias);
        hv[2] = (_Float16)(acc[ns][2] + bias);
        hv[3] = (_Float16)(acc[ns][3] + bias);
        *(half4_t*)&ldsTr[ns * 16 + row][w * 16 + strip * 4] = hv;
    }
    __syncthreads();

    {
        const int n = tid >> 2, jg = tid & 3;
        uint4 v0 = *(const uint4*)&ldsTr[n][jg * 16];
        uint4 v1 = *(const uint4*)&ldsTr[n][jg * 16 + 8];
        const int ng = n0 + n;
        const int h = ng >> 5, d = ng & 31;
        const int b = m0 >> 9, j0 = m0 & 511;
        _Float16* dst = &WhT[(((size_t)b * Hv + h) * Dv + d) * Nv + j0 + jg * 16];
        *(uint4*)dst = v0;
        *(uint4*)(dst + 8) = v1;
    }
}

// ---------------------------------------------------------------------------
// Kernel 2: e12 = x @ Wa + cba  (unchanged from round 4)
// ---------------------------------------------------------------------------
__global__ __launch_bounds__(256) void e12_kernel(const float* __restrict__ x,
                                                  const float* __restrict__ Wa,
                                                  const float* __restrict__ cba,
                                                  float* __restrict__ e1,
                                                  float* __restrict__ e2) {
    __shared__ float WaS[Ev][16];
    __shared__ float cbaS[16];

    const int tid = threadIdx.x;
    const int m0 = blockIdx.x * 32;

    #pragma unroll
    for (int u = 0; u < 4; ++u) {
        int f = tid + u * 256;
        *(float4*)&WaS[f >> 2][(f & 3) * 4] = *(const float4*)&Wa[f * 4];
    }
    if (tid < 16) cbaS[tid] = cba[tid];
    __syncthreads();

    const int r = tid >> 3;
    const int q = (tid >> 1) & 3;
    const int kh = tid & 1;
    const int m = m0 + r;

    const float* xr = &x[(size_t)m * Ev + kh * 128];
    float4 acc = {0.f, 0.f, 0.f, 0.f};

    #pragma unroll 8
    for (int it = 0; it < 32; ++it) {
        float4 xv = *(const float4*)&xr[it * 4];
        const int kb = kh * 128 + it * 4;
        float4 w0 = *(const float4*)&WaS[kb + 0][q * 4];
        float4 w1 = *(const float4*)&WaS[kb + 1][q * 4];
        float4 w2 = *(const float4*)&WaS[kb + 2][q * 4];
        float4 w3 = *(const float4*)&WaS[kb + 3][q * 4];
        acc.x += xv.x * w0.x + xv.y * w1.x + xv.z * w2.x + xv.w * w3.x;
        acc.y += xv.x * w0.y + xv.y * w1.y + xv.z * w2.y + xv.w * w3.y;
        acc.z += xv.x * w0.z + xv.y * w1.z + xv.z * w2.z + xv.w * w3.z;
        acc.w += xv.x * w0.w + xv.y * w1.w + xv.z * w2.w + xv.w * w3.w;
    }

    acc.x += __shfl_xor(acc.x, 1);
    acc.y += __shfl_xor(acc.y, 1);
    acc.z += __shfl_xor(acc.z, 1);
    acc.w += __shfl_xor(acc.w, 1);

    if (kh == 0) {
        const int b = m >> 9, i = m & 511;
        #pragma unroll
        for (int cc = 0; cc < 4; ++cc) {
            const int c = q * 4 + cc;
            const float val = ((cc == 0) ? acc.x : (cc == 1) ? acc.y : (cc == 2) ? acc.z : acc.w)
                              + cbaS[c];
            const int h = c >> 1;
            float* dst = (c & 1) ? e2 : e1;
            dst[(((b << 3) + h) << 9) + i] = val;
        }
    }
}

// ---------------------------------------------------------------------------
// Kernel 3: fused masked-lrelu-softmax + PV via MFMA 16x16x32 f16.
// Round-5 rewrite: zero global loads and zero transcendentals in the t-loop.
//  - A row mask: 512 bits in 16 VGPRs (loaded once).
//  - exp factorization: p = max(E1p*E2p[j], E1n*E2n[j])  [z>0 <=> pp>pn],
//    masked by bit. E1p/E1n: 2 exps/row. E2p/E2n: LDS tables (2 exps/j).
// ---------------------------------------------------------------------------
__global__ __launch_bounds__(256) void attn_kernel(const unsigned int* __restrict__ Abm,
                                                   const _Float16* __restrict__ WhT,
                                                   const float* __restrict__ e1g,
                                                   const float* __restrict__ e2g,
                                                   float* __restrict__ out) {
    __shared__ _Float16 whT[Dv * Nv];  // 32KB, 16B-blocks XOR-swizzled by (d&7)
    __shared__ float E2pS[Nv];         // 2KB
    __shared__ float E2nS[Nv];         // 2KB

    const int tid = threadIdx.x;
    const int i0 = blockIdx.x * 64;
    const int h = blockIdx.y;
    const int b = blockIdx.z;
    const int bh = (b << 3) + h;

    const _Float16* src = WhT + (size_t)bh * (Dv * Nv);
    #pragma unroll
    for (int u = 0; u < 8; ++u) {
        int f = tid + u * 256;
        int d = f >> 6, blk = f & 63;
        uint4 v = *(const uint4*)(src + d * Nv + blk * 8);
        *(uint4*)&whT[d * Nv + ((blk ^ (d & 7)) * 8)] = v;
    }
    {
        float ea = e2g[(bh << 9) + tid] * LOG2E;
        E2pS[tid] = __builtin_amdgcn_exp2f(ea);
        E2nS[tid] = __builtin_amdgcn_exp2f(0.2f * ea);
        float eb = e2g[(bh << 9) + tid + 256] * LOG2E;
        E2pS[tid + 256] = __builtin_amdgcn_exp2f(eb);
        E2nS[tid + 256] = __builtin_amdgcn_exp2f(0.2f * eb);
    }
    __syncthreads();

    const int w = tid >> 6;
    const int lane = tid & 63;
    const int row = lane & 15;
    const int strip = lane >> 4;
    const int i = i0 + (w << 4) + row;

    const float e1v = e1g[(bh << 9) + i] * LOG2E;
    const float E1p = __builtin_amdgcn_exp2f(e1v);
    const float E1n = __builtin_amdgcn_exp2f(0.2f * e1v);

    // row bitmask: 512 bits = 16 dwords (constant-indexed after full unroll)
    const uint4* bmp = (const uint4*)&Abm[((size_t)b * Nv + i) << 4];
    const uint4 bm0 = bmp[0], bm1 = bmp[1], bm2 = bmp[2], bm3 = bmp[3];
    const unsigned int dwarr[16] = {bm0.x, bm0.y, bm0.z, bm0.w,
                                    bm1.x, bm1.y, bm1.z, bm1.w,
                                    bm2.x, bm2.y, bm2.z, bm2.w,
                                    bm3.x, bm3.y, bm3.z, bm3.w};
    const int sh = strip << 3;  // bit shift AND float offset (8 j's per strip)

    const int d0 = lane & 15;
    const int sw = d0 & 7;
    const _Float16* brow0 = &whT[d0 * Nv];
    const _Float16* brow1 = &whT[(16 + d0) * Nv];

    f32x4 acc0 = {0.f, 0.f, 0.f, 0.f};
    f32x4 acc1 = {0.f, 0.f, 0.f, 0.f};
    float denom = 0.f;

    #pragma unroll
    for (int t = 0; t < 16; ++t) {
        const unsigned int byte_ = (dwarr[t] >> sh) & 0xFFu;
        const float4 p0 = *(const float4*)&E2pS[t * 32 + sh];
        const float4 p1 = *(const float4*)&E2pS[t * 32 + sh + 4];
        const float4 n0 = *(const float4*)&E2nS[t * 32 + sh];
        const float4 n1 = *(const float4*)&E2nS[t * 32 + sh + 4];

        const float q0 = (byte_ & 1u)   ? fmaxf(E1p * p0.x, E1n * n0.x) : 0.f;
        const float q1 = (byte_ & 2u)   ? fmaxf(E1p * p0.y, E1n * n0.y) : 0.f;
        const float q2 = (byte_ & 4u)   ? fmaxf(E1p * p0.z, E1n * n0.z) : 0.f;
        const float q3 = (byte_ & 8u)   ? fmaxf(E1p * p0.w, E1n * n0.w) : 0.f;
        const float q4 = (byte_ & 16u)  ? fmaxf(E1p * p1.x, E1n * n1.x) : 0.f;
        const float q5 = (byte_ & 32u)  ? fmaxf(E1p * p1.y, E1n * n1.y) : 0.f;
        const float q6 = (byte_ & 64u)  ? fmaxf(E1p * p1.z, E1n * n1.z) : 0.f;
        const float q7 = (byte_ & 128u) ? fmaxf(E1p * p1.w, E1n * n1.w) : 0.f;

        denom += ((q0 + q1) + (q2 + q3)) + ((q4 + q5) + (q6 + q7));

        half8 af;
        af[0] = (_Float16)q0; af[1] = (_Float16)q1;
        af[2] = (_Float16)q2; af[3] = (_Float16)q3;
        af[4] = (_Float16)q4; af[5] = (_Float16)q5;
        af[6] = (_Float16)q6; af[7] = (_Float16)q7;

        const int blk = ((t << 2) + strip) ^ sw;
        half8 b0 = *(const half8*)(brow0 + blk * 8);
        half8 b1 = *(const half8*)(brow1 + blk * 8);
        acc0 = __builtin_amdgcn_mfma_f32_16x16x32_f16(af, b0, acc0, 0, 0, 0);
        acc1 = __builtin_amdgcn_mfma_f32_16x16x32_f16(af, b1, acc1, 0, 0, 0);
    }

    denom += __shfl_xor(denom, 16);
    denom += __shfl_xor(denom, 32);

    #pragma unroll
    for (int e = 0; e < 4; ++e) {
        const float dn = __shfl(denom, (strip << 2) + e);
        const float rv = (dn > 0.f) ? (1.f / dn) : 0.f;
        const int orow = i0 + (w << 4) + (strip << 2) + e;
        float* orp = &out[((size_t)b * Nv + orow) * Ev + (h << 5)];
        orp[d0] = fmaxf(acc0[e] * rv, 0.f);
        orp[16 + d0] = fmaxf(acc1[e] * rv, 0.f);
    }
}

// ---------------------------------------------------------------------------
// Workspace: WT 128KB | Wa 16KB | cba 256B | WhT 4MB | e1 256KB | e2 256KB |
//            Abm 512KB
// ---------------------------------------------------------------------------
extern "C" void kernel_launch(void* const* d_in, const int* in_sizes, int n_in,
                              void* d_out, int out_size, void* d_ws, size_t ws_size,
                              hipStream_t stream) {
    const float* x  = (const float*)d_in[0];
    const float* A  = (const float*)d_in[1];
    const float* W  = (const float*)d_in[2];
    const float* bW = (const float*)d_in[3];
    const float* a  = (const float*)d_in[4];
    const float* ba = (const float*)d_in[5];
    float* out = (float*)d_out;

    char* ws = (char*)d_ws;
    _Float16* WT  = (_Float16*)ws;                               // 128KB
    float*    Wa  = (float*)(ws + 131072);                       // 16KB
    float*    cba = (float*)(ws + 131072 + 16384);               // 256B
    _Float16* WhT = (_Float16*)(ws + 131072 + 16384 + 256);      // 4MB
    float*    e1  = (float*)(ws + 131072 + 16384 + 256 + 4194304);
    float*    e2  = e1 + (size_t)Bv * Hv * Nv;
    unsigned int* Abm = (unsigned int*)(e2 + (size_t)Bv * Hv * Nv);  // 512KB

    prep_kernel<<<2129, 256, 0, stream>>>(W, a, bW, ba, A, WT, Wa, cba, Abm);
    whT_gemm<<<dim3(Bv * Nv / 64, Ev / 64), 256, 0, stream>>>(x, WT, bW, WhT);
    e12_kernel<<<dim3(Bv * Nv / 32), 256, 0, stream>>>(x, Wa, cba, e1, e2);
    attn_kernel<<<dim3(Nv / 64, Hv, Bv), 256, 0, stream>>>(Abm, WhT, e1, e2, out);
}

// Round 6
// 42.752 us; speedup vs baseline: 3.0898x; 1.0589x over previous
//
#include <hip/hip_runtime.h>
#include <math.h>

// Problem constants
#define Bv 16
#define Nv 512
#define Ev 256
#define Hv 8
#define Dv 32   // E/H
#define LOG2E 1.44269504088896340736f

typedef _Float16 half8 __attribute__((ext_vector_type(8)));
typedef _Float16 half4_t __attribute__((ext_vector_type(4)));
typedef float f32x4 __attribute__((ext_vector_type(4)));

// ---------------------------------------------------------------------------
// Kernel 1 (fused pre): block-specialized, all parts independent.
//  blk <  512   : WhT GEMM tile (reads x, W directly; self-contained W panel)
//  512..527     : Wa[e][c] = sum_f W[e][f] * a[f][c]
//  528          : cba[c] = sum_f bW[f]*a[f][c] + ba[c]
//  529..2576    : Abm bit-pack of A via ballot
// ---------------------------------------------------------------------------
__global__ __launch_bounds__(256) void fused_pre(const float* __restrict__ x,
                                                 const float* __restrict__ W,
                                                 const float* __restrict__ bW,
                                                 const float* __restrict__ aP,
                                                 const float* __restrict__ ba,
                                                 const float* __restrict__ A,
                                                 _Float16* __restrict__ WhT,
                                                 float* __restrict__ Wa,
                                                 float* __restrict__ cba,
                                                 unsigned int* __restrict__ Abm) {
    __shared__ _Float16 Wp[64][264];   // [n][k] W panel, f16 (33.8 KB)
    __shared__ _Float16 xs[64][40];    // [m][k] x tile f16 (5.1 KB)
    __shared__ _Float16 ldsTr[64][72]; // epilogue transpose (9.2 KB)

    const int tid = threadIdx.x;
    const int blk = blockIdx.x;

    if (blk < 512) {
        // ---------------- WhT GEMM ----------------
        const int m0 = (blk >> 2) * 64;
        const int n0 = (blk & 3) * 64;
        const int w = tid >> 6;
        const int lane = tid & 63;
        const int row = lane & 15;
        const int strip = lane >> 4;

        // stage W panel: thread = one k-row, transposed f16 scalar writes
        // (addr stride 2B over lanes -> 2-way bank alias = free)
        {
            const float* wrow = &W[(size_t)tid * Ev + n0];
            #pragma unroll
            for (int u = 0; u < 16; ++u) {
                float4 v = *(const float4*)&wrow[u * 4];
                Wp[u * 4 + 0][tid] = (_Float16)v.x;
                Wp[u * 4 + 1][tid] = (_Float16)v.y;
                Wp[u * 4 + 2][tid] = (_Float16)v.z;
                Wp[u * 4 + 3][tid] = (_Float16)v.w;
            }
        }

        f32x4 acc[4] = {{0.f, 0.f, 0.f, 0.f}, {0.f, 0.f, 0.f, 0.f},
                        {0.f, 0.f, 0.f, 0.f}, {0.f, 0.f, 0.f, 0.f}};
        const int sr = tid >> 2;
        const int skg = (tid & 3) * 8;

        for (int k0 = 0; k0 < Ev; k0 += 32) {
            {
                const float* xp = &x[(size_t)(m0 + sr) * Ev + k0 + skg];
                float4 v0 = *(const float4*)xp;
                float4 v1 = *(const float4*)(xp + 4);
                half8 hv;
                hv[0] = (_Float16)v0.x; hv[1] = (_Float16)v0.y;
                hv[2] = (_Float16)v0.z; hv[3] = (_Float16)v0.w;
                hv[4] = (_Float16)v1.x; hv[5] = (_Float16)v1.y;
                hv[6] = (_Float16)v1.z; hv[7] = (_Float16)v1.w;
                *(half8*)&xs[sr][skg] = hv;
            }
            __syncthreads();

            half8 af = *(const half8*)&xs[w * 16 + row][strip * 8];
            #pragma unroll
            for (int ns = 0; ns < 4; ++ns) {
                half8 bf = *(const half8*)&Wp[ns * 16 + row][k0 + strip * 8];
                acc[ns] = __builtin_amdgcn_mfma_f32_16x16x32_f16(af, bf, acc[ns], 0, 0, 0);
            }
            __syncthreads();
        }

        #pragma unroll
        for (int ns = 0; ns < 4; ++ns) {
            const float bias = bW[n0 + ns * 16 + row];
            half4_t hv;
            hv[0] = (_Float16)(acc[ns][0] + bias);
            hv[1] = (_Float16)(acc[ns][1] + bias);
            hv[2] = (_Float16)(acc[ns][2] + bias);
            hv[3] = (_Float16)(acc[ns][3] + bias);
            *(half4_t*)&ldsTr[ns * 16 + row][w * 16 + strip * 4] = hv;
        }
        __syncthreads();

        {
            const int n = tid >> 2, jg = tid & 3;
            uint4 v0 = *(const uint4*)&ldsTr[n][jg * 16];
            uint4 v1 = *(const uint4*)&ldsTr[n][jg * 16 + 8];
            const int ng = n0 + n;
            const int h = ng >> 5, d = ng & 31;
            const int b = m0 >> 9, j0 = m0 & 511;
            _Float16* dst = &WhT[(((size_t)b * Hv + h) * Dv + d) * Nv + j0 + jg * 16];
            *(uint4*)dst = v0;
            *(uint4*)(dst + 8) = v1;
        }
    } else if (blk < 528) {
        const int e = (blk - 512) * 16 + (tid >> 4);
        const int c = tid & 15;
        float dot = 0.f;
        for (int k4 = 0; k4 < 64; ++k4) {
            float4 wv = *(const float4*)&W[(size_t)e * Ev + k4 * 4];
            dot += wv.x * aP[(k4 * 4 + 0) * 16 + c];
            dot += wv.y * aP[(k4 * 4 + 1) * 16 + c];
            dot += wv.z * aP[(k4 * 4 + 2) * 16 + c];
            dot += wv.w * aP[(k4 * 4 + 3) * 16 + c];
        }
        Wa[e * 16 + c] = dot;
    } else if (blk == 528) {
        if (tid < 16) {
            float d = ba[tid];
            for (int k = 0; k < Ev; ++k) d += bW[k] * aP[k * 16 + tid];
            cba[tid] = d;
        }
    } else {
        const int ablk = blk - 529;
        const int w = tid >> 6, lane = tid & 63;
        const size_t base = (size_t)ablk * 2048 + w * 512;
        #pragma unroll
        for (int r = 0; r < 8; ++r) {
            const size_t f = base + r * 64 + lane;
            const bool pred = A[f] > 0.5f;
            unsigned long long m = __ballot(pred);
            if (lane == 0) *(unsigned long long*)&Abm[f >> 5] = m;
        }
    }
}

// ---------------------------------------------------------------------------
// Kernel 2: e12 = x @ Wa + cba  (unchanged)
// ---------------------------------------------------------------------------
__global__ __launch_bounds__(256) void e12_kernel(const float* __restrict__ x,
                                                  const float* __restrict__ Wa,
                                                  const float* __restrict__ cba,
                                                  float* __restrict__ e1,
                                                  float* __restrict__ e2) {
    __shared__ float WaS[Ev][16];
    __shared__ float cbaS[16];

    const int tid = threadIdx.x;
    const int m0 = blockIdx.x * 32;

    #pragma unroll
    for (int u = 0; u < 4; ++u) {
        int f = tid + u * 256;
        *(float4*)&WaS[f >> 2][(f & 3) * 4] = *(const float4*)&Wa[f * 4];
    }
    if (tid < 16) cbaS[tid] = cba[tid];
    __syncthreads();

    const int r = tid >> 3;
    const int q = (tid >> 1) & 3;
    const int kh = tid & 1;
    const int m = m0 + r;

    const float* xr = &x[(size_t)m * Ev + kh * 128];
    float4 acc = {0.f, 0.f, 0.f, 0.f};

    #pragma unroll 8
    for (int it = 0; it < 32; ++it) {
        float4 xv = *(const float4*)&xr[it * 4];
        const int kb = kh * 128 + it * 4;
        float4 w0 = *(const float4*)&WaS[kb + 0][q * 4];
        float4 w1 = *(const float4*)&WaS[kb + 1][q * 4];
        float4 w2 = *(const float4*)&WaS[kb + 2][q * 4];
        float4 w3 = *(const float4*)&WaS[kb + 3][q * 4];
        acc.x += xv.x * w0.x + xv.y * w1.x + xv.z * w2.x + xv.w * w3.x;
        acc.y += xv.x * w0.y + xv.y * w1.y + xv.z * w2.y + xv.w * w3.y;
        acc.z += xv.x * w0.z + xv.y * w1.z + xv.z * w2.z + xv.w * w3.z;
        acc.w += xv.x * w0.w + xv.y * w1.w + xv.z * w2.w + xv.w * w3.w;
    }

    acc.x += __shfl_xor(acc.x, 1);
    acc.y += __shfl_xor(acc.y, 1);
    acc.z += __shfl_xor(acc.z, 1);
    acc.w += __shfl_xor(acc.w, 1);

    if (kh == 0) {
        const int b = m >> 9, i = m & 511;
        #pragma unroll
        for (int cc = 0; cc < 4; ++cc) {
            const int c = q * 4 + cc;
            const float val = ((cc == 0) ? acc.x : (cc == 1) ? acc.y : (cc == 2) ? acc.z : acc.w)
                              + cbaS[c];
            const int h = c >> 1;
            float* dst = (c & 1) ? e2 : e1;
            dst[(((b << 3) + h) << 9) + i] = val;
        }
    }
}

// ---------------------------------------------------------------------------
// Kernel 3: fused masked-softmax + PV, MFMA 16x16x32 f16.
// Each wave owns TWO 16-row tiles (32 rows) -> E2-table reads and whT B-frag
// reads are shared across both tiles: 6 b128 serve 4 MFMA (was 6 per 2).
// Block = 256 thr / 4 waves = 128 rows; grid (4, H, B) = 512 blocks.
// ---------------------------------------------------------------------------
__global__ __launch_bounds__(256) void attn_kernel(const unsigned int* __restrict__ Abm,
                                                   const _Float16* __restrict__ WhT,
                                                   const float* __restrict__ e1g,
                                                   const float* __restrict__ e2g,
                                                   float* __restrict__ out) {
    __shared__ _Float16 whT[Dv * Nv];  // 32KB, 16B-blocks XOR-swizzled by (d&7)
    __shared__ float E2pS[Nv];
    __shared__ float E2nS[Nv];

    const int tid = threadIdx.x;
    const int i0 = blockIdx.x * 128;
    const int h = blockIdx.y;
    const int b = blockIdx.z;
    const int bh = (b << 3) + h;

    const _Float16* src = WhT + (size_t)bh * (Dv * Nv);
    #pragma unroll
    for (int u = 0; u < 8; ++u) {
        int f = tid + u * 256;
        int d = f >> 6, bq = f & 63;
        uint4 v = *(const uint4*)(src + d * Nv + bq * 8);
        *(uint4*)&whT[d * Nv + ((bq ^ (d & 7)) * 8)] = v;
    }
    {
        float ea = e2g[(bh << 9) + tid] * LOG2E;
        E2pS[tid] = __builtin_amdgcn_exp2f(ea);
        E2nS[tid] = __builtin_amdgcn_exp2f(0.2f * ea);
        float eb = e2g[(bh << 9) + tid + 256] * LOG2E;
        E2pS[tid + 256] = __builtin_amdgcn_exp2f(eb);
        E2nS[tid + 256] = __builtin_amdgcn_exp2f(0.2f * eb);
    }
    __syncthreads();

    const int w = tid >> 6;
    const int lane = tid & 63;
    const int row = lane & 15;
    const int strip = lane >> 4;
    const int iA = i0 + (w << 5) + row;
    const int iB = iA + 16;

    const float e1A = e1g[(bh << 9) + iA] * LOG2E;
    const float e1B = e1g[(bh << 9) + iB] * LOG2E;
    const float E1pA = __builtin_amdgcn_exp2f(e1A);
    const float E1nA = __builtin_amdgcn_exp2f(0.2f * e1A);
    const float E1pB = __builtin_amdgcn_exp2f(e1B);
    const float E1nB = __builtin_amdgcn_exp2f(0.2f * e1B);

    const uint4* bpA = (const uint4*)&Abm[((size_t)b * Nv + iA) << 4];
    const uint4 mA0 = bpA[0], mA1 = bpA[1], mA2 = bpA[2], mA3 = bpA[3];
    const uint4* bpB = (const uint4*)&Abm[((size_t)b * Nv + iB) << 4];
    const uint4 mB0 = bpB[0], mB1 = bpB[1], mB2 = bpB[2], mB3 = bpB[3];

    const int sh = strip << 3;
    const int d0 = lane & 15;
    const int sw = d0 & 7;
    const _Float16* brow0 = &whT[d0 * Nv];
    const _Float16* brow1 = &whT[(16 + d0) * Nv];

    f32x4 accA0 = {0.f, 0.f, 0.f, 0.f}, accA1 = accA0;
    f32x4 accB0 = accA0, accB1 = accA0;
    float denA = 0.f, denB = 0.f;

    #pragma unroll
    for (int t = 0; t < 16; ++t) {
        const uint4 mqA = (t >> 2) == 0 ? mA0 : (t >> 2) == 1 ? mA1 : (t >> 2) == 2 ? mA2 : mA3;
        const uint4 mqB = (t >> 2) == 0 ? mB0 : (t >> 2) == 1 ? mB1 : (t >> 2) == 2 ? mB2 : mB3;
        const unsigned int dwA = (t & 3) == 0 ? mqA.x : (t & 3) == 1 ? mqA.y : (t & 3) == 2 ? mqA.z : mqA.w;
        const unsigned int dwB = (t & 3) == 0 ? mqB.x : (t & 3) == 1 ? mqB.y : (t & 3) == 2 ? mqB.z : mqB.w;
        const unsigned int byA = (dwA >> sh) & 0xFFu;
        const unsigned int byB = (dwB >> sh) & 0xFFu;

        const float4 p0 = *(const float4*)&E2pS[t * 32 + sh];
        const float4 p1 = *(const float4*)&E2pS[t * 32 + sh + 4];
        const float4 n0 = *(const float4*)&E2nS[t * 32 + sh];
        const float4 n1 = *(const float4*)&E2nS[t * 32 + sh + 4];

        const float qA0 = (byA & 1u)   ? fmaxf(E1pA * p0.x, E1nA * n0.x) : 0.f;
        const float qA1 = (byA & 2u)   ? fmaxf(E1pA * p0.y, E1nA * n0.y) : 0.f;
        const float qA2 = (byA & 4u)   ? fmaxf(E1pA * p0.z, E1nA * n0.z) : 0.f;
        const float qA3 = (byA & 8u)   ? fmaxf(E1pA * p0.w, E1nA * n0.w) : 0.f;
        const float qA4 = (byA & 16u)  ? fmaxf(E1pA * p1.x, E1nA * n1.x) : 0.f;
        const float qA5 = (byA & 32u)  ? fmaxf(E1pA * p1.y, E1nA * n1.y) : 0.f;
        const float qA6 = (byA & 64u)  ? fmaxf(E1pA * p1.z, E1nA * n1.z) : 0.f;
        const float qA7 = (byA & 128u) ? fmaxf(E1pA * p1.w, E1nA * n1.w) : 0.f;
        const float qB0 = (byB & 1u)   ? fmaxf(E1pB * p0.x, E1nB * n0.x) : 0.f;
        const float qB1 = (byB & 2u)   ? fmaxf(E1pB * p0.y, E1nB * n0.y) : 0.f;
        const float qB2 = (byB & 4u)   ? fmaxf(E1pB * p0.z, E1nB * n0.z) : 0.f;
        const float qB3 = (byB & 8u)   ? fmaxf(E1pB * p0.w, E1nB * n0.w) : 0.f;
        const float qB4 = (byB & 16u)  ? fmaxf(E1pB * p1.x, E1nB * n1.x) : 0.f;
        const float qB5 = (byB & 32u)  ? fmaxf(E1pB * p1.y, E1nB * n1.y) : 0.f;
        const float qB6 = (byB & 64u)  ? fmaxf(E1pB * p1.z, E1nB * n1.z) : 0.f;
        const float qB7 = (byB & 128u) ? fmaxf(E1pB * p1.w, E1nB * n1.w) : 0.f;

        denA += ((qA0 + qA1) + (qA2 + qA3)) + ((qA4 + qA5) + (qA6 + qA7));
        denB += ((qB0 + qB1) + (qB2 + qB3)) + ((qB4 + qB5) + (qB6 + qB7));

        half8 afA, afB;
        afA[0] = (_Float16)qA0; afA[1] = (_Float16)qA1;
        afA[2] = (_Float16)qA2; afA[3] = (_Float16)qA3;
        afA[4] = (_Float16)qA4; afA[5] = (_Float16)qA5;
        afA[6] = (_Float16)qA6; afA[7] = (_Float16)qA7;
        afB[0] = (_Float16)qB0; afB[1] = (_Float16)qB1;
        afB[2] = (_Float16)qB2; afB[3] = (_Float16)qB3;
        afB[4] = (_Float16)qB4; afB[5] = (_Float16)qB5;
        afB[6] = (_Float16)qB6; afB[7] = (_Float16)qB7;

        const int bq = ((t << 2) + strip) ^ sw;
        half8 b0 = *(const half8*)(brow0 + bq * 8);
        half8 b1 = *(const half8*)(brow1 + bq * 8);
        accA0 = __builtin_amdgcn_mfma_f32_16x16x32_f16(afA, b0, accA0, 0, 0, 0);
        accA1 = __builtin_amdgcn_mfma_f32_16x16x32_f16(afA, b1, accA1, 0, 0, 0);
        accB0 = __builtin_amdgcn_mfma_f32_16x16x32_f16(afB, b0, accB0, 0, 0, 0);
        accB1 = __builtin_amdgcn_mfma_f32_16x16x32_f16(afB, b1, accB1, 0, 0, 0);
    }

    denA += __shfl_xor(denA, 16);
    denA += __shfl_xor(denA, 32);
    denB += __shfl_xor(denB, 16);
    denB += __shfl_xor(denB, 32);

    #pragma unroll
    for (int e = 0; e < 4; ++e) {
        const float dnA = __shfl(denA, (strip << 2) + e);
        const float rvA = (dnA > 0.f) ? (1.f / dnA) : 0.f;
        const int orA = i0 + (w << 5) + (strip << 2) + e;
        float* opA = &out[((size_t)b * Nv + orA) * Ev + (h << 5)];
        opA[d0] = fmaxf(accA0[e] * rvA, 0.f);
        opA[16 + d0] = fmaxf(accA1[e] * rvA, 0.f);

        const float dnB = __shfl(denB, (strip << 2) + e);
        const float rvB = (dnB > 0.f) ? (1.f / dnB) : 0.f;
        const int orB = orA + 16;
        float* opB = &out[((size_t)b * Nv + orB) * Ev + (h << 5)];
        opB[d0] = fmaxf(accB0[e] * rvB, 0.f);
        opB[16 + d0] = fmaxf(accB1[e] * rvB, 0.f);
    }
}

// ---------------------------------------------------------------------------
// Workspace layout (bytes from d_ws):
//   Wa      @ 0         (16 KB)
//   cba     @ 16384     (64 B)
//   e1      @ 32768     (256 KB)
//   e2      @ 294912    (256 KB)
//   Abm     @ 557056    (512 KB)
//   WhT     @ 1572864   (4 MB)
// ---------------------------------------------------------------------------
extern "C" void kernel_launch(void* const* d_in, const int* in_sizes, int n_in,
                              void* d_out, int out_size, void* d_ws, size_t ws_size,
                              hipStream_t stream) {
    const float* x  = (const float*)d_in[0];
    const float* A  = (const float*)d_in[1];
    const float* W  = (const float*)d_in[2];
    const float* bW = (const float*)d_in[3];
    const float* a  = (const float*)d_in[4];
    const float* ba = (const float*)d_in[5];
    float* out = (float*)d_out;

    char* ws = (char*)d_ws;
    float*        Wa  = (float*)(ws);
    float*        cba = (float*)(ws + 16384);
    float*        e1  = (float*)(ws + 32768);
    float*        e2  = (float*)(ws + 294912);
    unsigned int* Abm = (unsigned int*)(ws + 557056);
    _Float16*     WhT = (_Float16*)(ws + 1572864);

    fused_pre<<<2577, 256, 0, stream>>>(x, W, bW, a, ba, A, WhT, Wa, cba, Abm);
    e12_kernel<<<dim3(Bv * Nv / 32), 256, 0, stream>>>(x, Wa, cba, e1, e2);
    attn_kernel<<<dim3(Nv / 128, Hv, Bv), 256, 0, stream>>>(Abm, WhT, e1, e2, out);
}

// Round 8
// 41.879 us; speedup vs baseline: 3.1543x; 1.0208x over previous
//
#include <hip/hip_runtime.h>
#include <math.h>

// Problem constants
#define Bv 16
#define Nv 512
#define Ev 256
#define Hv 8
#define Dv 32   // E/H
#define LOG2E 1.44269504088896340736f

typedef _Float16 half8 __attribute__((ext_vector_type(8)));
typedef _Float16 half4_t __attribute__((ext_vector_type(4)));
typedef __fp16 fp16x2 __attribute__((ext_vector_type(2)));   // cvt_pkrtz result type
typedef float f32x4 __attribute__((ext_vector_type(4)));

// ---------------------------------------------------------------------------
// Kernel 1 (fused pre): block-specialized, all parts independent.
//  blk <  512   : WhT GEMM tile (x double-buffered; self-contained W panel)
//  512..527     : WaT[c][e] = f16( sum_f W[e][f] * a[f][c] )
//  528          : cba[c] = sum_f bW[f]*a[f][c] + ba[c]
//  529..2576    : Abm bit-pack of A via ballot
// ---------------------------------------------------------------------------
__global__ __launch_bounds__(256) void fused_pre(const float* __restrict__ x,
                                                 const float* __restrict__ W,
                                                 const float* __restrict__ bW,
                                                 const float* __restrict__ aP,
                                                 const float* __restrict__ ba,
                                                 const float* __restrict__ A,
                                                 _Float16* __restrict__ WhT,
                                                 _Float16* __restrict__ WaT,
                                                 float* __restrict__ cba,
                                                 unsigned int* __restrict__ Abm) {
    __shared__ _Float16 Wp[64][264];      // [n][k] W panel f16 (33.8 KB)
    __shared__ _Float16 xs[2][64][40];    // [m][k] x tile f16, double-buffered (10 KB)
    __shared__ _Float16 ldsTr[64][72];    // epilogue transpose (9.2 KB)

    const int tid = threadIdx.x;
    const int blk = blockIdx.x;

    if (blk < 512) {
        // ---------------- WhT GEMM ----------------
        const int m0 = (blk >> 2) * 64;
        const int n0 = (blk & 3) * 64;
        const int w = tid >> 6;
        const int lane = tid & 63;
        const int row = lane & 15;
        const int strip = lane >> 4;

        // stage W panel: thread = one k-row, transposed f16 scalar writes
        {
            const float* wrow = &W[(size_t)tid * Ev + n0];
            #pragma unroll
            for (int u = 0; u < 16; ++u) {
                float4 v = *(const float4*)&wrow[u * 4];
                Wp[u * 4 + 0][tid] = (_Float16)v.x;
                Wp[u * 4 + 1][tid] = (_Float16)v.y;
                Wp[u * 4 + 2][tid] = (_Float16)v.z;
                Wp[u * 4 + 3][tid] = (_Float16)v.w;
            }
        }

        const int sr = tid >> 2;
        const int skg = (tid & 3) * 8;
        const float* xrow = &x[(size_t)(m0 + sr) * Ev + skg];

        // stage first x tile (k0 = 0)
        {
            float4 v0 = *(const float4*)xrow;
            float4 v1 = *(const float4*)(xrow + 4);
            half8 hv;
            hv[0] = (_Float16)v0.x; hv[1] = (_Float16)v0.y;
            hv[2] = (_Float16)v0.z; hv[3] = (_Float16)v0.w;
            hv[4] = (_Float16)v1.x; hv[5] = (_Float16)v1.y;
            hv[6] = (_Float16)v1.z; hv[7] = (_Float16)v1.w;
            *(half8*)&xs[0][sr][skg] = hv;
        }
        __syncthreads();

        f32x4 acc[4] = {{0.f, 0.f, 0.f, 0.f}, {0.f, 0.f, 0.f, 0.f},
                        {0.f, 0.f, 0.f, 0.f}, {0.f, 0.f, 0.f, 0.f}};
        int cur = 0;

        #pragma unroll
        for (int it = 0; it < 8; ++it) {
            float4 nv0, nv1;
            if (it < 7) {  // prefetch next x tile into regs (overlaps MFMA)
                nv0 = *(const float4*)(xrow + (it + 1) * 32);
                nv1 = *(const float4*)(xrow + (it + 1) * 32 + 4);
            }

            half8 af = *(const half8*)&xs[cur][w * 16 + row][strip * 8];
            #pragma unroll
            for (int ns = 0; ns < 4; ++ns) {
                half8 bf = *(const half8*)&Wp[ns * 16 + row][it * 32 + strip * 8];
                acc[ns] = __builtin_amdgcn_mfma_f32_16x16x32_f16(af, bf, acc[ns], 0, 0, 0);
            }

            if (it < 7) {
                half8 hv;
                hv[0] = (_Float16)nv0.x; hv[1] = (_Float16)nv0.y;
                hv[2] = (_Float16)nv0.z; hv[3] = (_Float16)nv0.w;
                hv[4] = (_Float16)nv1.x; hv[5] = (_Float16)nv1.y;
                hv[6] = (_Float16)nv1.z; hv[7] = (_Float16)nv1.w;
                *(half8*)&xs[cur ^ 1][sr][skg] = hv;
                __syncthreads();
                cur ^= 1;
            }
        }

        #pragma unroll
        for (int ns = 0; ns < 4; ++ns) {
            const float bias = bW[n0 + ns * 16 + row];
            half4_t hv;
            hv[0] = (_Float16)(acc[ns][0] + bias);
            hv[1] = (_Float16)(acc[ns][1] + bias);
            hv[2] = (_Float16)(acc[ns][2] + bias);
            hv[3] = (_Float16)(acc[ns][3] + bias);
            *(half4_t*)&ldsTr[ns * 16 + row][w * 16 + strip * 4] = hv;
        }
        __syncthreads();

        {
            const int n = tid >> 2, jg = tid & 3;
            uint4 v0 = *(const uint4*)&ldsTr[n][jg * 16];
            uint4 v1 = *(const uint4*)&ldsTr[n][jg * 16 + 8];
            const int ng = n0 + n;
            const int h = ng >> 5, d = ng & 31;
            const int b = m0 >> 9, j0 = m0 & 511;
            _Float16* dst = &WhT[(((size_t)b * Hv + h) * Dv + d) * Nv + j0 + jg * 16];
            *(uint4*)dst = v0;
            *(uint4*)(dst + 8) = v1;
        }
    } else if (blk < 528) {
        const int e = (blk - 512) * 16 + (tid >> 4);
        const int c = tid & 15;
        float dot = 0.f;
        for (int k4 = 0; k4 < 64; ++k4) {
            float4 wv = *(const float4*)&W[(size_t)e * Ev + k4 * 4];
            dot += wv.x * aP[(k4 * 4 + 0) * 16 + c];
            dot += wv.y * aP[(k4 * 4 + 1) * 16 + c];
            dot += wv.z * aP[(k4 * 4 + 2) * 16 + c];
            dot += wv.w * aP[(k4 * 4 + 3) * 16 + c];
        }
        WaT[(size_t)c * Ev + e] = (_Float16)dot;  // [c][k] for e12 B-frags
    } else if (blk == 528) {
        if (tid < 16) {
            float d = ba[tid];
            for (int k = 0; k < Ev; ++k) d += bW[k] * aP[k * 16 + tid];
            cba[tid] = d;
        }
    } else {
        const int ablk = blk - 529;
        const int w = tid >> 6, lane = tid & 63;
        const size_t base = (size_t)ablk * 2048 + w * 512;
        #pragma unroll
        for (int r = 0; r < 8; ++r) {
            const size_t f = base + r * 64 + lane;
            const bool pred = A[f] > 0.5f;
            unsigned long long m = __ballot(pred);
            if (lane == 0) *(unsigned long long*)&Abm[f >> 5] = m;
        }
    }
}

// ---------------------------------------------------------------------------
// Kernel 2: e12 = x @ Wa + cba via MFMA 16x16x32 f16, LDS-free.
// 1 wave / 16 rows / block; A-frags from global x (cvt_pkrtz), B-frags from
// WaT[c][k] (f16, k-contiguous). D: col=lane&15 = c, row = strip*4+e = m.
// ---------------------------------------------------------------------------
__global__ __launch_bounds__(64) void e12_mfma(const float* __restrict__ x,
                                               const _Float16* __restrict__ WaT,
                                               const float* __restrict__ cba,
                                               float* __restrict__ e1,
                                               float* __restrict__ e2) {
    const int lane = threadIdx.x;
    const int m0 = blockIdx.x * 16;
    const int l15 = lane & 15;
    const int strip = lane >> 4;

    const float* xr = &x[(size_t)(m0 + l15) * Ev + strip * 8];       // A: row m
    const _Float16* wr = &WaT[(size_t)l15 * Ev + strip * 8];         // B: col c

    f32x4 acc = {0.f, 0.f, 0.f, 0.f};
    #pragma unroll
    for (int kt = 0; kt < 8; ++kt) {
        float4 a0 = *(const float4*)&xr[kt * 32];
        float4 a1 = *(const float4*)&xr[kt * 32 + 4];
        fp16x2 h0 = __builtin_amdgcn_cvt_pkrtz(a0.x, a0.y);
        fp16x2 h1 = __builtin_amdgcn_cvt_pkrtz(a0.z, a0.w);
        fp16x2 h2 = __builtin_amdgcn_cvt_pkrtz(a1.x, a1.y);
        fp16x2 h3 = __builtin_amdgcn_cvt_pkrtz(a1.z, a1.w);
        uint4 U;
        U.x = __builtin_bit_cast(unsigned int, h0);
        U.y = __builtin_bit_cast(unsigned int, h1);
        U.z = __builtin_bit_cast(unsigned int, h2);
        U.w = __builtin_bit_cast(unsigned int, h3);
        half8 af = __builtin_bit_cast(half8, U);
        half8 bf = *(const half8*)&wr[kt * 32];
        acc = __builtin_amdgcn_mfma_f32_16x16x32_f16(af, bf, acc, 0, 0, 0);
    }

    const int c = l15;
    const float cb = cba[c];
    const int h = c >> 1;
    float* dst = (c & 1) ? e2 : e1;
    #pragma unroll
    for (int e = 0; e < 4; ++e) {
        const int m = m0 + strip * 4 + e;
        const int b = m >> 9, i = m & 511;
        dst[(((b << 3) + h) << 9) + i] = acc[e] + cb;
    }
}

// ---------------------------------------------------------------------------
// Kernel 3: fused masked-softmax + PV, MFMA 16x16x32 f16.
// Two 16-row tiles per wave; pass-1 packs q's to f16 via cvt_pkrtz; f32 denom.
// ---------------------------------------------------------------------------
__global__ __launch_bounds__(256) void attn_kernel(const unsigned int* __restrict__ Abm,
                                                   const _Float16* __restrict__ WhT,
                                                   const float* __restrict__ e1g,
                                                   const float* __restrict__ e2g,
                                                   float* __restrict__ out) {
    __shared__ _Float16 whT[Dv * Nv];  // 32KB, 16B-blocks XOR-swizzled by (d&7)
    __shared__ float E2pS[Nv];
    __shared__ float E2nS[Nv];

    const int tid = threadIdx.x;
    const int i0 = blockIdx.x * 128;
    const int h = blockIdx.y;
    const int b = blockIdx.z;
    const int bh = (b << 3) + h;

    const _Float16* src = WhT + (size_t)bh * (Dv * Nv);
    #pragma unroll
    for (int u = 0; u < 8; ++u) {
        int f = tid + u * 256;
        int d = f >> 6, bq = f & 63;
        uint4 v = *(const uint4*)(src + d * Nv + bq * 8);
        *(uint4*)&whT[d * Nv + ((bq ^ (d & 7)) * 8)] = v;
    }
    {
        float ea = e2g[(bh << 9) + tid] * LOG2E;
        E2pS[tid] = __builtin_amdgcn_exp2f(ea);
        E2nS[tid] = __builtin_amdgcn_exp2f(0.2f * ea);
        float eb = e2g[(bh << 9) + tid + 256] * LOG2E;
        E2pS[tid + 256] = __builtin_amdgcn_exp2f(eb);
        E2nS[tid + 256] = __builtin_amdgcn_exp2f(0.2f * eb);
    }
    __syncthreads();

    const int w = tid >> 6;
    const int lane = tid & 63;
    const int row = lane & 15;
    const int strip = lane >> 4;
    const int iA = i0 + (w << 5) + row;
    const int iB = iA + 16;

    const float e1A = e1g[(bh << 9) + iA] * LOG2E;
    const float e1B = e1g[(bh << 9) + iB] * LOG2E;
    const float E1pA = __builtin_amdgcn_exp2f(e1A);
    const float E1nA = __builtin_amdgcn_exp2f(0.2f * e1A);
    const float E1pB = __builtin_amdgcn_exp2f(e1B);
    const float E1nB = __builtin_amdgcn_exp2f(0.2f * e1B);

    const uint4* bpA = (const uint4*)&Abm[((size_t)b * Nv + iA) << 4];
    const uint4 mA0 = bpA[0], mA1 = bpA[1], mA2 = bpA[2], mA3 = bpA[3];
    const uint4* bpB = (const uint4*)&Abm[((size_t)b * Nv + iB) << 4];
    const uint4 mB0 = bpB[0], mB1 = bpB[1], mB2 = bpB[2], mB3 = bpB[3];

    const int sh = strip << 3;
    const int d0 = lane & 15;
    const int sw = d0 & 7;
    const _Float16* brow0 = &whT[d0 * Nv];
    const _Float16* brow1 = &whT[(16 + d0) * Nv];

    f32x4 accA0 = {0.f, 0.f, 0.f, 0.f}, accA1 = accA0;
    f32x4 accB0 = accA0, accB1 = accA0;
    float denA = 0.f, denB = 0.f;

    #pragma unroll
    for (int t = 0; t < 16; ++t) {
        const uint4 mqA = (t >> 2) == 0 ? mA0 : (t >> 2) == 1 ? mA1 : (t >> 2) == 2 ? mA2 : mA3;
        const uint4 mqB = (t >> 2) == 0 ? mB0 : (t >> 2) == 1 ? mB1 : (t >> 2) == 2 ? mB2 : mB3;
        const unsigned int dwA = (t & 3) == 0 ? mqA.x : (t & 3) == 1 ? mqA.y : (t & 3) == 2 ? mqA.z : mqA.w;
        const unsigned int dwB = (t & 3) == 0 ? mqB.x : (t & 3) == 1 ? mqB.y : (t & 3) == 2 ? mqB.z : mqB.w;
        const unsigned int byA = (dwA >> sh) & 0xFFu;
        const unsigned int byB = (dwB >> sh) & 0xFFu;

        const float4 p0 = *(const float4*)&E2pS[t * 32 + sh];
        const float4 p1 = *(const float4*)&E2pS[t * 32 + sh + 4];
        const float4 n0 = *(const float4*)&E2nS[t * 32 + sh];
        const float4 n1 = *(const float4*)&E2nS[t * 32 + sh + 4];

        const float qA0 = (byA & 1u)   ? fmaxf(E1pA * p0.x, E1nA * n0.x) : 0.f;
        const float qA1 = (byA & 2u)   ? fmaxf(E1pA * p0.y, E1nA * n0.y) : 0.f;
        const float qA2 = (byA & 4u)   ? fmaxf(E1pA * p0.z, E1nA * n0.z) : 0.f;
        const float qA3 = (byA & 8u)   ? fmaxf(E1pA * p0.w, E1nA * n0.w) : 0.f;
        const float qA4 = (byA & 16u)  ? fmaxf(E1pA * p1.x, E1nA * n1.x) : 0.f;
        const float qA5 = (byA & 32u)  ? fmaxf(E1pA * p1.y, E1nA * n1.y) : 0.f;
        const float qA6 = (byA & 64u)  ? fmaxf(E1pA * p1.z, E1nA * n1.z) : 0.f;
        const float qA7 = (byA & 128u) ? fmaxf(E1pA * p1.w, E1nA * n1.w) : 0.f;
        const float qB0 = (byB & 1u)   ? fmaxf(E1pB * p0.x, E1nB * n0.x) : 0.f;
        const float qB1 = (byB & 2u)   ? fmaxf(E1pB * p0.y, E1nB * n0.y) : 0.f;
        const float qB2 = (byB & 4u)   ? fmaxf(E1pB * p0.z, E1nB * n0.z) : 0.f;
        const float qB3 = (byB & 8u)   ? fmaxf(E1pB * p0.w, E1nB * n0.w) : 0.f;
        const float qB4 = (byB & 16u)  ? fmaxf(E1pB * p1.x, E1nB * n1.x) : 0.f;
        const float qB5 = (byB & 32u)  ? fmaxf(E1pB * p1.y, E1nB * n1.y) : 0.f;
        const float qB6 = (byB & 64u)  ? fmaxf(E1pB * p1.z, E1nB * n1.z) : 0.f;
        const float qB7 = (byB & 128u) ? fmaxf(E1pB * p1.w, E1nB * n1.w) : 0.f;

        denA += ((qA0 + qA1) + (qA2 + qA3)) + ((qA4 + qA5) + (qA6 + qA7));
        denB += ((qB0 + qB1) + (qB2 + qB3)) + ((qB4 + qB5) + (qB6 + qB7));

        // pack to f16 pairs (RTZ) straight into MFMA A-frags
        fp16x2 a01 = __builtin_amdgcn_cvt_pkrtz(qA0, qA1);
        fp16x2 a23 = __builtin_amdgcn_cvt_pkrtz(qA2, qA3);
        fp16x2 a45 = __builtin_amdgcn_cvt_pkrtz(qA4, qA5);
        fp16x2 a67 = __builtin_amdgcn_cvt_pkrtz(qA6, qA7);
        fp16x2 b01 = __builtin_amdgcn_cvt_pkrtz(qB0, qB1);
        fp16x2 b23 = __builtin_amdgcn_cvt_pkrtz(qB2, qB3);
        fp16x2 b45 = __builtin_amdgcn_cvt_pkrtz(qB4, qB5);
        fp16x2 b67 = __builtin_amdgcn_cvt_pkrtz(qB6, qB7);

        uint4 UA, UB;
        UA.x = __builtin_bit_cast(unsigned int, a01);
        UA.y = __builtin_bit_cast(unsigned int, a23);
        UA.z = __builtin_bit_cast(unsigned int, a45);
        UA.w = __builtin_bit_cast(unsigned int, a67);
        UB.x = __builtin_bit_cast(unsigned int, b01);
        UB.y = __builtin_bit_cast(unsigned int, b23);
        UB.z = __builtin_bit_cast(unsigned int, b45);
        UB.w = __builtin_bit_cast(unsigned int, b67);
        half8 afA = __builtin_bit_cast(half8, UA);
        half8 afB = __builtin_bit_cast(half8, UB);

        const int bq = ((t << 2) + strip) ^ sw;
        half8 b0 = *(const half8*)(brow0 + bq * 8);
        half8 b1 = *(const half8*)(brow1 + bq * 8);
        accA0 = __builtin_amdgcn_mfma_f32_16x16x32_f16(afA, b0, accA0, 0, 0, 0);
        accA1 = __builtin_amdgcn_mfma_f32_16x16x32_f16(afA, b1, accA1, 0, 0, 0);
        accB0 = __builtin_amdgcn_mfma_f32_16x16x32_f16(afB, b0, accB0, 0, 0, 0);
        accB1 = __builtin_amdgcn_mfma_f32_16x16x32_f16(afB, b1, accB1, 0, 0, 0);
    }

    denA += __shfl_xor(denA, 16);
    denA += __shfl_xor(denA, 32);
    denB += __shfl_xor(denB, 16);
    denB += __shfl_xor(denB, 32);

    #pragma unroll
    for (int e = 0; e < 4; ++e) {
        const float dnA = __shfl(denA, (strip << 2) + e);
        const float rvA = (dnA > 0.f) ? (1.f / dnA) : 0.f;
        const int orA = i0 + (w << 5) + (strip << 2) + e;
        float* opA = &out[((size_t)b * Nv + orA) * Ev + (h << 5)];
        opA[d0] = fmaxf(accA0[e] * rvA, 0.f);
        opA[16 + d0] = fmaxf(accA1[e] * rvA, 0.f);

        const float dnB = __shfl(denB, (strip << 2) + e);
        const float rvB = (dnB > 0.f) ? (1.f / dnB) : 0.f;
        const int orB = orA + 16;
        float* opB = &out[((size_t)b * Nv + orB) * Ev + (h << 5)];
        opB[d0] = fmaxf(accB0[e] * rvB, 0.f);
        opB[16 + d0] = fmaxf(accB1[e] * rvB, 0.f);
    }
}

// ---------------------------------------------------------------------------
// Workspace layout (bytes from d_ws):
//   WaT f16 @ 0         (8 KB)
//   cba     @ 16384     (64 B)
//   e1      @ 32768     (256 KB)
//   e2      @ 294912    (256 KB)
//   Abm     @ 557056    (512 KB)
//   WhT     @ 1572864   (4 MB)
// ---------------------------------------------------------------------------
extern "C" void kernel_launch(void* const* d_in, const int* in_sizes, int n_in,
                              void* d_out, int out_size, void* d_ws, size_t ws_size,
                              hipStream_t stream) {
    const float* x  = (const float*)d_in[0];
    const float* A  = (const float*)d_in[1];
    const float* W  = (const float*)d_in[2];
    const float* bW = (const float*)d_in[3];
    const float* a  = (const float*)d_in[4];
    const float* ba = (const float*)d_in[5];
    float* out = (float*)d_out;

    char* ws = (char*)d_ws;
    _Float16*     WaT = (_Float16*)(ws);
    float*        cba = (float*)(ws + 16384);
    float*        e1  = (float*)(ws + 32768);
    float*        e2  = (float*)(ws + 294912);
    unsigned int* Abm = (unsigned int*)(ws + 557056);
    _Float16*     WhT = (_Float16*)(ws + 1572864);

    fused_pre<<<2577, 256, 0, stream>>>(x, W, bW, a, ba, A, WhT, WaT, cba, Abm);
    e12_mfma<<<Bv * Nv / 16, 64, 0, stream>>>(x, WaT, cba, e1, e2);
    attn_kernel<<<dim3(Nv / 128, Hv, Bv), 256, 0, stream>>>(Abm, WhT, e1, e2, out);
}

// Round 9
// 40.139 us; speedup vs baseline: 3.2910x; 1.0433x over previous
//
#include <hip/hip_runtime.h>
#include <math.h>

// Problem constants
#define Bv 16
#define Nv 512
#define Ev 256
#define Hv 8
#define Dv 32   // E/H
#define LOG2E 1.44269504088896340736f

typedef _Float16 half8 __attribute__((ext_vector_type(8)));
typedef _Float16 half4_t __attribute__((ext_vector_type(4)));
typedef __fp16 fp16x2 __attribute__((ext_vector_type(2)));
typedef float f32x4 __attribute__((ext_vector_type(4)));

// ---------------------------------------------------------------------------
// Kernel 1 (fused pre): block-specialized.
//  blk <  512 : WhT GEMM tile (x double-buffered, W panel in LDS) + e12
//               n-quarter partial via 2 extra MFMAs on the ldsTr tile.
//  blk >= 512 : Abm bit-pack of A via ballot (2048 blocks).
//
// e12part[nq][c][b][j] = sum_{f in 64-quarter nq} f16(Wh[b,j,f]) * f16(a[f,c])
// (deterministic: exactly one GEMM block writes each element)
// ---------------------------------------------------------------------------
__global__ __launch_bounds__(256) void fused_pre(const float* __restrict__ x,
                                                 const float* __restrict__ W,
                                                 const float* __restrict__ bW,
                                                 const float* __restrict__ aP,
                                                 const float* __restrict__ A,
                                                 _Float16* __restrict__ WhT,
                                                 float* __restrict__ e12part,
                                                 unsigned int* __restrict__ Abm) {
    __shared__ _Float16 Wp[64][264];      // [n][k] W panel f16 (33.8 KB)
    __shared__ _Float16 xs[2][64][40];    // [m][k] x tile f16, double-buffered
    __shared__ _Float16 ldsTr[64][68];    // [n][m] Wh tile (stride 68: no 4-way bank alias)

    const int tid = threadIdx.x;
    const int blk = blockIdx.x;

    if (blk < 512) {
        // ---------------- WhT GEMM ----------------
        const int m0 = (blk >> 2) * 64;
        const int n0 = (blk & 3) * 64;
        const int w = tid >> 6;
        const int lane = tid & 63;
        const int row = lane & 15;
        const int strip = lane >> 4;

        // stage W panel
        {
            const float* wrow = &W[(size_t)tid * Ev + n0];
            #pragma unroll
            for (int u = 0; u < 16; ++u) {
                float4 v = *(const float4*)&wrow[u * 4];
                Wp[u * 4 + 0][tid] = (_Float16)v.x;
                Wp[u * 4 + 1][tid] = (_Float16)v.y;
                Wp[u * 4 + 2][tid] = (_Float16)v.z;
                Wp[u * 4 + 3][tid] = (_Float16)v.w;
            }
        }

        const int sr = tid >> 2;
        const int skg = (tid & 3) * 8;
        const float* xrow = &x[(size_t)(m0 + sr) * Ev + skg];

        {
            float4 v0 = *(const float4*)xrow;
            float4 v1 = *(const float4*)(xrow + 4);
            half8 hv;
            hv[0] = (_Float16)v0.x; hv[1] = (_Float16)v0.y;
            hv[2] = (_Float16)v0.z; hv[3] = (_Float16)v0.w;
            hv[4] = (_Float16)v1.x; hv[5] = (_Float16)v1.y;
            hv[6] = (_Float16)v1.z; hv[7] = (_Float16)v1.w;
            *(half8*)&xs[0][sr][skg] = hv;
        }
        __syncthreads();

        f32x4 acc[4] = {{0.f, 0.f, 0.f, 0.f}, {0.f, 0.f, 0.f, 0.f},
                        {0.f, 0.f, 0.f, 0.f}, {0.f, 0.f, 0.f, 0.f}};
        int cur = 0;

        #pragma unroll
        for (int it = 0; it < 8; ++it) {
            float4 nv0, nv1;
            if (it < 7) {
                nv0 = *(const float4*)(xrow + (it + 1) * 32);
                nv1 = *(const float4*)(xrow + (it + 1) * 32 + 4);
            }

            half8 af = *(const half8*)&xs[cur][w * 16 + row][strip * 8];
            #pragma unroll
            for (int ns = 0; ns < 4; ++ns) {
                half8 bf = *(const half8*)&Wp[ns * 16 + row][it * 32 + strip * 8];
                acc[ns] = __builtin_amdgcn_mfma_f32_16x16x32_f16(af, bf, acc[ns], 0, 0, 0);
            }

            if (it < 7) {
                half8 hv;
                hv[0] = (_Float16)nv0.x; hv[1] = (_Float16)nv0.y;
                hv[2] = (_Float16)nv0.z; hv[3] = (_Float16)nv0.w;
                hv[4] = (_Float16)nv1.x; hv[5] = (_Float16)nv1.y;
                hv[6] = (_Float16)nv1.z; hv[7] = (_Float16)nv1.w;
                *(half8*)&xs[cur ^ 1][sr][skg] = hv;
                __syncthreads();
                cur ^= 1;
            }
        }

        // epilogue: add bias, cvt f16, transpose via LDS: ldsTr[n_local][m_local]
        #pragma unroll
        for (int ns = 0; ns < 4; ++ns) {
            const float bias = bW[n0 + ns * 16 + row];
            half4_t hv;
            hv[0] = (_Float16)(acc[ns][0] + bias);
            hv[1] = (_Float16)(acc[ns][1] + bias);
            hv[2] = (_Float16)(acc[ns][2] + bias);
            hv[3] = (_Float16)(acc[ns][3] + bias);
            *(half4_t*)&ldsTr[ns * 16 + row][w * 16 + strip * 4] = hv;
        }
        __syncthreads();

        // WhT global writeout (coalesced 32B)
        {
            const int n = tid >> 2, jg = tid & 3;
            uint4 v0 = *(const uint4*)&ldsTr[n][jg * 16];
            uint4 v1 = *(const uint4*)&ldsTr[n][jg * 16 + 8];
            const int ng = n0 + n;
            const int h = ng >> 5, d = ng & 31;
            const int b = m0 >> 9, j0 = m0 & 511;
            _Float16* dst = &WhT[(((size_t)b * Hv + h) * Dv + d) * Nv + j0 + jg * 16];
            *(uint4*)dst = v0;
            *(uint4*)(dst + 8) = v1;
        }

        // e12 n-quarter partial: D[j=64][c=16] = ldsTr^T(64j x 64f) @ a(64f x 16c)
        // wave w owns j-rows w*16..w*16+15; 2 MFMAs over K=64.
        {
            const int nq = n0 >> 6;
            const int b = m0 >> 9, j0 = m0 & 511;
            const int jA = lane & 15;     // A-frag row (j), also B-frag col (c)
            f32x4 eacc = {0.f, 0.f, 0.f, 0.f};
            #pragma unroll
            for (int kh = 0; kh < 2; ++kh) {
                half8 af, bf;
                #pragma unroll
                for (int e = 0; e < 8; ++e) {
                    const int kf = kh * 32 + strip * 8 + e;
                    af[e] = ldsTr[kf][w * 16 + jA];
                    bf[e] = (_Float16)aP[(n0 + kf) * 16 + jA];
                }
                eacc = __builtin_amdgcn_mfma_f32_16x16x32_f16(af, bf, eacc, 0, 0, 0);
            }
            // D: col=lane&15=c, row=strip*4+reg -> j = w*16 + strip*4 + reg
            const int c = jA;
            float* dst = &e12part[(((size_t)(nq * 16 + c)) * Bv + b) * Nv +
                                  j0 + w * 16 + strip * 4];
            *(f32x4*)dst = eacc;
        }
    } else {
        const int ablk = blk - 512;
        const int w = tid >> 6, lane = tid & 63;
        const size_t base = (size_t)ablk * 2048 + w * 512;
        #pragma unroll
        for (int r = 0; r < 8; ++r) {
            const size_t f = base + r * 64 + lane;
            const bool pred = A[f] > 0.5f;
            unsigned long long m = __ballot(pred);
            if (lane == 0) *(unsigned long long*)&Abm[f >> 5] = m;
        }
    }
}

// ---------------------------------------------------------------------------
// Kernel 2: fused masked-softmax + PV, MFMA 16x16x32 f16.
// 128 threads (2 waves), 64 rows/block (2 tiles/wave), grid (8, H, B) = 1024
// blocks -> 4 blocks/CU (LDS 36KB). e1/e2 assembled from the 4 n-quarter
// partials + ba.
// ---------------------------------------------------------------------------
__global__ __launch_bounds__(128) void attn_kernel(const unsigned int* __restrict__ Abm,
                                                   const _Float16* __restrict__ WhT,
                                                   const float* __restrict__ e12part,
                                                   const float* __restrict__ baP,
                                                   float* __restrict__ out) {
    __shared__ _Float16 whT[Dv * Nv];  // 32KB, 16B-blocks XOR-swizzled by (d&7)
    __shared__ float E2pS[Nv];
    __shared__ float E2nS[Nv];

    const int tid = threadIdx.x;
    const int i0 = blockIdx.x * 64;
    const int h = blockIdx.y;
    const int b = blockIdx.z;
    const int bh = (b << 3) + h;

    const _Float16* src = WhT + (size_t)bh * (Dv * Nv);
    #pragma unroll
    for (int u = 0; u < 16; ++u) {
        int f = tid + u * 128;
        int d = f >> 6, bq = f & 63;
        uint4 v = *(const uint4*)(src + d * Nv + bq * 8);
        *(uint4*)&whT[d * Nv + ((bq ^ (d & 7)) * 8)] = v;
    }
    {
        // e2 table: sum 4 n-quarter partials (float4 per quarter) + ba[2h+1]
        const float ba2 = baP[2 * h + 1];
        const int c2 = 2 * h + 1;
        float4 s = {0.f, 0.f, 0.f, 0.f};
        #pragma unroll
        for (int nq = 0; nq < 4; ++nq) {
            float4 v = *(const float4*)&e12part[(((size_t)(nq * 16 + c2)) * Bv + b) * Nv + tid * 4];
            s.x += v.x; s.y += v.y; s.z += v.z; s.w += v.w;
        }
        const float v0 = (s.x + ba2) * LOG2E;
        const float v1 = (s.y + ba2) * LOG2E;
        const float v2 = (s.z + ba2) * LOG2E;
        const float v3 = (s.w + ba2) * LOG2E;
        E2pS[tid * 4 + 0] = __builtin_amdgcn_exp2f(v0);
        E2pS[tid * 4 + 1] = __builtin_amdgcn_exp2f(v1);
        E2pS[tid * 4 + 2] = __builtin_amdgcn_exp2f(v2);
        E2pS[tid * 4 + 3] = __builtin_amdgcn_exp2f(v3);
        E2nS[tid * 4 + 0] = __builtin_amdgcn_exp2f(0.2f * v0);
        E2nS[tid * 4 + 1] = __builtin_amdgcn_exp2f(0.2f * v1);
        E2nS[tid * 4 + 2] = __builtin_amdgcn_exp2f(0.2f * v2);
        E2nS[tid * 4 + 3] = __builtin_amdgcn_exp2f(0.2f * v3);
    }
    __syncthreads();

    const int w = tid >> 6;          // 0..1
    const int lane = tid & 63;
    const int row = lane & 15;
    const int strip = lane >> 4;
    const int iA = i0 + (w << 5) + row;
    const int iB = iA + 16;

    // e1 for rows iA, iB: sum partials + ba[2h]
    const int c1 = 2 * h;
    float e1Araw = baP[c1], e1Braw = baP[c1];
    #pragma unroll
    for (int nq = 0; nq < 4; ++nq) {
        const float* p = &e12part[(((size_t)(nq * 16 + c1)) * Bv + b) * Nv];
        e1Araw += p[iA];
        e1Braw += p[iB];
    }
    const float e1A = e1Araw * LOG2E;
    const float e1B = e1Braw * LOG2E;
    const float E1pA = __builtin_amdgcn_exp2f(e1A);
    const float E1nA = __builtin_amdgcn_exp2f(0.2f * e1A);
    const float E1pB = __builtin_amdgcn_exp2f(e1B);
    const float E1nB = __builtin_amdgcn_exp2f(0.2f * e1B);

    const uint4* bpA = (const uint4*)&Abm[((size_t)b * Nv + iA) << 4];
    const uint4 mA0 = bpA[0], mA1 = bpA[1], mA2 = bpA[2], mA3 = bpA[3];
    const uint4* bpB = (const uint4*)&Abm[((size_t)b * Nv + iB) << 4];
    const uint4 mB0 = bpB[0], mB1 = bpB[1], mB2 = bpB[2], mB3 = bpB[3];

    const int sh = strip << 3;
    const int d0 = lane & 15;
    const int sw = d0 & 7;
    const _Float16* brow0 = &whT[d0 * Nv];
    const _Float16* brow1 = &whT[(16 + d0) * Nv];

    f32x4 accA0 = {0.f, 0.f, 0.f, 0.f}, accA1 = accA0;
    f32x4 accB0 = accA0, accB1 = accA0;
    float denA = 0.f, denB = 0.f;

    #pragma unroll
    for (int t = 0; t < 16; ++t) {
        const uint4 mqA = (t >> 2) == 0 ? mA0 : (t >> 2) == 1 ? mA1 : (t >> 2) == 2 ? mA2 : mA3;
        const uint4 mqB = (t >> 2) == 0 ? mB0 : (t >> 2) == 1 ? mB1 : (t >> 2) == 2 ? mB2 : mB3;
        const unsigned int dwA = (t & 3) == 0 ? mqA.x : (t & 3) == 1 ? mqA.y : (t & 3) == 2 ? mqA.z : mqA.w;
        const unsigned int dwB = (t & 3) == 0 ? mqB.x : (t & 3) == 1 ? mqB.y : (t & 3) == 2 ? mqB.z : mqB.w;
        const unsigned int byA = (dwA >> sh) & 0xFFu;
        const unsigned int byB = (dwB >> sh) & 0xFFu;

        const float4 p0 = *(const float4*)&E2pS[t * 32 + sh];
        const float4 p1 = *(const float4*)&E2pS[t * 32 + sh + 4];
        const float4 n0 = *(const float4*)&E2nS[t * 32 + sh];
        const float4 n1 = *(const float4*)&E2nS[t * 32 + sh + 4];

        const float qA0 = (byA & 1u)   ? fmaxf(E1pA * p0.x, E1nA * n0.x) : 0.f;
        const float qA1 = (byA & 2u)   ? fmaxf(E1pA * p0.y, E1nA * n0.y) : 0.f;
        const float qA2 = (byA & 4u)   ? fmaxf(E1pA * p0.z, E1nA * n0.z) : 0.f;
        const float qA3 = (byA & 8u)   ? fmaxf(E1pA * p0.w, E1nA * n0.w) : 0.f;
        const float qA4 = (byA & 16u)  ? fmaxf(E1pA * p1.x, E1nA * n1.x) : 0.f;
        const float qA5 = (byA & 32u)  ? fmaxf(E1pA * p1.y, E1nA * n1.y) : 0.f;
        const float qA6 = (byA & 64u)  ? fmaxf(E1pA * p1.z, E1nA * n1.z) : 0.f;
        const float qA7 = (byA & 128u) ? fmaxf(E1pA * p1.w, E1nA * n1.w) : 0.f;
        const float qB0 = (byB & 1u)   ? fmaxf(E1pB * p0.x, E1nB * n0.x) : 0.f;
        const float qB1 = (byB & 2u)   ? fmaxf(E1pB * p0.y, E1nB * n0.y) : 0.f;
        const float qB2 = (byB & 4u)   ? fmaxf(E1pB * p0.z, E1nB * n0.z) : 0.f;
        const float qB3 = (byB & 8u)   ? fmaxf(E1pB * p0.w, E1nB * n0.w) : 0.f;
        const float qB4 = (byB & 16u)  ? fmaxf(E1pB * p1.x, E1nB * n1.x) : 0.f;
        const float qB5 = (byB & 32u)  ? fmaxf(E1pB * p1.y, E1nB * n1.y) : 0.f;
        const float qB6 = (byB & 64u)  ? fmaxf(E1pB * p1.z, E1nB * n1.z) : 0.f;
        const float qB7 = (byB & 128u) ? fmaxf(E1pB * p1.w, E1nB * n1.w) : 0.f;

        denA += ((qA0 + qA1) + (qA2 + qA3)) + ((qA4 + qA5) + (qA6 + qA7));
        denB += ((qB0 + qB1) + (qB2 + qB3)) + ((qB4 + qB5) + (qB6 + qB7));

        fp16x2 a01 = __builtin_amdgcn_cvt_pkrtz(qA0, qA1);
        fp16x2 a23 = __builtin_amdgcn_cvt_pkrtz(qA2, qA3);
        fp16x2 a45 = __builtin_amdgcn_cvt_pkrtz(qA4, qA5);
        fp16x2 a67 = __builtin_amdgcn_cvt_pkrtz(qA6, qA7);
        fp16x2 b01 = __builtin_amdgcn_cvt_pkrtz(qB0, qB1);
        fp16x2 b23 = __builtin_amdgcn_cvt_pkrtz(qB2, qB3);
        fp16x2 b45 = __builtin_amdgcn_cvt_pkrtz(qB4, qB5);
        fp16x2 b67 = __builtin_amdgcn_cvt_pkrtz(qB6, qB7);

        uint4 UA, UB;
        UA.x = __builtin_bit_cast(unsigned int, a01);
        UA.y = __builtin_bit_cast(unsigned int, a23);
        UA.z = __builtin_bit_cast(unsigned int, a45);
        UA.w = __builtin_bit_cast(unsigned int, a67);
        UB.x = __builtin_bit_cast(unsigned int, b01);
        UB.y = __builtin_bit_cast(unsigned int, b23);
        UB.z = __builtin_bit_cast(unsigned int, b45);
        UB.w = __builtin_bit_cast(unsigned int, b67);
        half8 afA = __builtin_bit_cast(half8, UA);
        half8 afB = __builtin_bit_cast(half8, UB);

        const int bq = ((t << 2) + strip) ^ sw;
        half8 b0 = *(const half8*)(brow0 + bq * 8);
        half8 b1 = *(const half8*)(brow1 + bq * 8);
        accA0 = __builtin_amdgcn_mfma_f32_16x16x32_f16(afA, b0, accA0, 0, 0, 0);
        accA1 = __builtin_amdgcn_mfma_f32_16x16x32_f16(afA, b1, accA1, 0, 0, 0);
        accB0 = __builtin_amdgcn_mfma_f32_16x16x32_f16(afB, b0, accB0, 0, 0, 0);
        accB1 = __builtin_amdgcn_mfma_f32_16x16x32_f16(afB, b1, accB1, 0, 0, 0);
    }

    denA += __shfl_xor(denA, 16);
    denA += __shfl_xor(denA, 32);
    denB += __shfl_xor(denB, 16);
    denB += __shfl_xor(denB, 32);

    #pragma unroll
    for (int e = 0; e < 4; ++e) {
        const float dnA = __shfl(denA, (strip << 2) + e);
        const float rvA = (dnA > 0.f) ? (1.f / dnA) : 0.f;
        const int orA = i0 + (w << 5) + (strip << 2) + e;
        float* opA = &out[((size_t)b * Nv + orA) * Ev + (h << 5)];
        opA[d0] = fmaxf(accA0[e] * rvA, 0.f);
        opA[16 + d0] = fmaxf(accA1[e] * rvA, 0.f);

        const float dnB = __shfl(denB, (strip << 2) + e);
        const float rvB = (dnB > 0.f) ? (1.f / dnB) : 0.f;
        const int orB = orA + 16;
        float* opB = &out[((size_t)b * Nv + orB) * Ev + (h << 5)];
        opB[d0] = fmaxf(accB0[e] * rvB, 0.f);
        opB[16 + d0] = fmaxf(accB1[e] * rvB, 0.f);
    }
}

// ---------------------------------------------------------------------------
// Workspace layout (bytes from d_ws):
//   e12part @ 0        (4nq x 16c x 16b x 512j f32 = 2 MB)
//   Abm     @ 2097152  (512 KB)
//   WhT     @ 2621440  (4 MB)
// ---------------------------------------------------------------------------
extern "C" void kernel_launch(void* const* d_in, const int* in_sizes, int n_in,
                              void* d_out, int out_size, void* d_ws, size_t ws_size,
                              hipStream_t stream) {
    const float* x  = (const float*)d_in[0];
    const float* A  = (const float*)d_in[1];
    const float* W  = (const float*)d_in[2];
    const float* bW = (const float*)d_in[3];
    const float* a  = (const float*)d_in[4];
    const float* ba = (const float*)d_in[5];
    float* out = (float*)d_out;

    char* ws = (char*)d_ws;
    float*        e12part = (float*)(ws);
    unsigned int* Abm     = (unsigned int*)(ws + 2097152);
    _Float16*     WhT     = (_Float16*)(ws + 2621440);

    fused_pre<<<2560, 256, 0, stream>>>(x, W, bW, a, A, WhT, e12part, Abm);
    attn_kernel<<<dim3(8, Hv, Bv), 128, 0, stream>>>(Abm, WhT, e12part, ba, out);
}